// Round 1
// baseline (1430.936 us; speedup 1.0000x reference)
//
#include <hip/hip_runtime.h>
#include <math.h>

// Problem constants
// B=8192, X=8, C=512, P=8, Y=1000, FAKE=16, F=2048, CLS=1000, IN_DIM=1024, SF=64
//
// Workspace layout (floats), total ~33.9M floats (~135.5 MB):
//  tex_n (8*1000*512) | g (128*512) | fb (128) | tex_a (128*512) | inv_img (65536)
//  cp (8192*1024, permuted cols: col' = x*128 + p*16 + d)
//  w1a (2048*1024, col-permuted+BN1-folded) | b1p (2048) | a1,c1 (1024 ea)
//  psum,psumsq (64*2048 ea) | h (8192*2048) | w2a (1000*2048) | b2p | a2,c2 (2048 ea)

__device__ __forceinline__ float waveSum(float v) {
#pragma unroll
    for (int o = 32; o > 0; o >>= 1) v += __shfl_xor(v, o);
    return v;
}

// ---------- tex_n = tex_f / (||row||+1e-6) * 64 ; one block per row ----------
__global__ __launch_bounds__(256) void k_rownorm(const float* __restrict__ in,
                                                 float* __restrict__ out) {
    int row = blockIdx.x, t = threadIdx.x;
    const float* r = in + (size_t)row * 512;
    float2 v = *(const float2*)(r + t * 2);
    float ss = v.x * v.x + v.y * v.y;
    ss = waveSum(ss);
    __shared__ float sred[4];
    if ((t & 63) == 0) sred[t >> 6] = ss;
    __syncthreads();
    float tot = sred[0] + sred[1] + sred[2] + sred[3];
    float sc = 64.f / (sqrtf(tot) + 1e-6f);
    *(float2*)(out + (size_t)row * 512 + t * 2) = make_float2(v.x * sc, v.y * sc);
}

// ---------- inv_img[r] = 64/(||img row r||+1e-6); 1 wave per row ----------
__global__ __launch_bounds__(256) void k_imgnorm(const float* __restrict__ in,
                                                 float* __restrict__ inv) {
    int row = blockIdx.x * 4 + (threadIdx.x >> 6);
    int lane = threadIdx.x & 63;
    const float* r = in + (size_t)row * 512 + lane * 8;
    float4 a = *(const float4*)r;
    float4 b = *(const float4*)(r + 4);
    float ss = a.x*a.x + a.y*a.y + a.z*a.z + a.w*a.w
             + b.x*b.x + b.y*b.y + b.z*b.z + b.w*b.w;
    ss = waveSum(ss);
    if (lane == 0) inv[row] = 64.f / (sqrtf(ss) + 1e-6f);
}

// ---------- g[bid, e] = sum_d fake_cls[bid,d]*fc_w[d,e]; fb[bid] = fcls . fc_b ----------
__global__ __launch_bounds__(256) void k_g(const float* __restrict__ fake_cls,
                                           const float* __restrict__ fc_w,
                                           const float* __restrict__ fc_b,
                                           float* __restrict__ g, float* __restrict__ fb) {
    int bid = blockIdx.x, t = threadIdx.x;
    __shared__ float fcls[512];
    __shared__ float sred[4];
    fcls[t]       = fake_cls[bid * 512 + t];
    fcls[t + 256] = fake_cls[bid * 512 + t + 256];
    __syncthreads();
    float a0 = 0.f, a1 = 0.f;
    for (int d = 0; d < 512; ++d) {
        float fv = fcls[d];
        a0 = fmaf(fv, fc_w[d * 512 + t], a0);
        a1 = fmaf(fv, fc_w[d * 512 + t + 256], a1);
    }
    g[bid * 512 + t]       = a0;
    g[bid * 512 + t + 256] = a1;
    float partial = fcls[t] * fc_b[t] + fcls[t + 256] * fc_b[t + 256];
    partial = waveSum(partial);
    if ((t & 63) == 0) sred[t >> 6] = partial;
    __syncthreads();
    if (t == 0) fb[bid] = sred[0] + sred[1] + sred[2] + sred[3];
}

// ---------- attention: logits -> softmax -> tex_a[bid,:] ----------
__global__ __launch_bounds__(256) void k_attn(const float* __restrict__ g,
                                              const float* __restrict__ fb,
                                              const float* __restrict__ texn,
                                              float* __restrict__ texa) {
    int bid = blockIdx.x;         // p*16 + fake_idx
    int p = bid >> 4;
    int t = threadIdx.x, lane = t & 63, wid = t >> 6;
    __shared__ float gsh[512];
    __shared__ float logits[1000];
    __shared__ float sred[4];
    gsh[t]       = g[bid * 512 + t];
    gsh[t + 256] = g[bid * 512 + t + 256];
    float fbv = fb[bid];
    __syncthreads();
    const float* tn = texn + (size_t)p * 1000 * 512;
    float4 ga = *(const float4*)&gsh[lane * 8];
    float4 gb = *(const float4*)&gsh[lane * 8 + 4];
    for (int y = wid; y < 1000; y += 4) {
        const float* tr = tn + (size_t)y * 512 + lane * 8;
        float4 va = *(const float4*)tr;
        float4 vb = *(const float4*)(tr + 4);
        float s = va.x*ga.x + va.y*ga.y + va.z*ga.z + va.w*ga.w
                + vb.x*gb.x + vb.y*gb.y + vb.z*gb.z + vb.w*gb.w;
        s = waveSum(s);
        if (lane == 0) logits[y] = s + fbv;
    }
    __syncthreads();
    // softmax (max-subtract)
    float m = -3.0e38f;
    for (int y = t; y < 1000; y += 256) m = fmaxf(m, logits[y]);
#pragma unroll
    for (int o = 32; o > 0; o >>= 1) m = fmaxf(m, __shfl_xor(m, o));
    if (lane == 0) sred[wid] = m;
    __syncthreads();
    m = fmaxf(fmaxf(sred[0], sred[1]), fmaxf(sred[2], sred[3]));
    __syncthreads();
    float ssum = 0.f;
    for (int y = t; y < 1000; y += 256) {
        float e = expf(logits[y] - m);
        logits[y] = e;
        ssum += e;
    }
    ssum = waveSum(ssum);
    if (lane == 0) sred[wid] = ssum;
    __syncthreads();
    float invd = 1.f / (sred[0] + sred[1] + sred[2] + sred[3]);
    // weighted sum of tex_n rows
    float acc0 = 0.f, acc1 = 0.f;
    for (int y = 0; y < 1000; ++y) {
        float w = logits[y];
        const float* tr = tn + (size_t)y * 512;
        acc0 = fmaf(w, tr[t], acc0);
        acc1 = fmaf(w, tr[t + 256], acc1);
    }
    texa[bid * 512 + t]       = acc0 * invd;
    texa[bid * 512 + t + 256] = acc1 * invd;
}

// ---------- column stats partials: 8192 rows, 128 rows per y-block ----------
__global__ __launch_bounds__(256) void k_colstat(const float* __restrict__ src,
                                                 float* __restrict__ ps,
                                                 float* __restrict__ pq, int ncols) {
    int col = blockIdx.x * 256 + threadIdx.x;
    int r0 = blockIdx.y * 128;
    const float* p = src + (size_t)r0 * ncols + col;
    float s = 0.f, q = 0.f;
    for (int r = 0; r < 128; ++r) {
        float v = p[(size_t)r * ncols];
        s += v;
        q = fmaf(v, v, q);
    }
    ps[(size_t)blockIdx.y * ncols + col] = s;
    pq[(size_t)blockIdx.y * ncols + col] = q;
}

// ---------- finalize BN scale/shift; PERM maps permuted col' -> true j ----------
template <bool PERM>
__global__ __launch_bounds__(256) void k_bnfin(const float* __restrict__ ps,
                                               const float* __restrict__ pq,
                                               const float* __restrict__ gam,
                                               const float* __restrict__ bet,
                                               float* __restrict__ a, float* __restrict__ c,
                                               int ncols) {
    int col = blockIdx.x * 256 + threadIdx.x;
    float S = 0.f, Q = 0.f;
    for (int i = 0; i < 64; ++i) {
        S += ps[(size_t)i * ncols + col];
        Q += pq[(size_t)i * ncols + col];
    }
    float mean = S * (1.f / 8192.f);
    float var = Q * (1.f / 8192.f) - mean * mean;
    int j = col;
    if (PERM) {
        int x = col >> 7, jj = col & 127, pp = jj >> 4, d = jj & 15;
        j = (pp << 7) + (x << 4) + d;
    }
    float av = gam[j] * rsqrtf(var + 1e-5f);
    a[col] = av;
    c[col] = bet[j] - mean * av;
}

// ---------- fold BN into weights: Wout[f,col] = W[f,j(col)]*a[col]; bout=bin+W.c ----------
template <bool PERM>
__global__ __launch_bounds__(256) void k_foldw(const float* __restrict__ W,
                                               const float* __restrict__ bin,
                                               const float* __restrict__ a,
                                               const float* __restrict__ c,
                                               float* __restrict__ Wout,
                                               float* __restrict__ bout, int Kdim) {
    int f = blockIdx.x, t = threadIdx.x;
    const float* wr = W + (size_t)f * Kdim;
    float* wo = Wout + (size_t)f * Kdim;
    float partial = 0.f;
    for (int col = t; col < Kdim; col += 256) {
        int j = col;
        if (PERM) {
            int x = col >> 7, jj = col & 127, pp = jj >> 4, d = jj & 15;
            j = (pp << 7) + (x << 4) + d;
        }
        float wv = wr[j];
        wo[col] = wv * a[col];
        partial = fmaf(wv, c[col], partial);
    }
    partial = waveSum(partial);
    __shared__ float sred[4];
    if ((t & 63) == 0) sred[t >> 6] = partial;
    __syncthreads();
    if (t == 0) bout[f] = bin[f] + sred[0] + sred[1] + sred[2] + sred[3];
}

// ---------- tiled fp32 GEMM: C[M,N] = A[M,K] @ B[N,K]^T (+epilogue) ----------
// EPI 0: C = acc * rowscale[row]        (cp GEMM)
// EPI 1: C = elu(acc + bias[col])       (hidden layer)
// EPI 2: C = acc + bias[col]            (output layer, col<N guarded)
template <int EPI>
__global__ __launch_bounds__(256) void gemm_tt(const float* __restrict__ A,
                                               const float* __restrict__ B,
                                               float* __restrict__ C, int M, int N, int K,
                                               const float* __restrict__ rowscale,
                                               const float* __restrict__ bias) {
    __shared__ float As[16][64];
    __shared__ float Bs[16][64];
    const int tid = threadIdx.x;
    const int tx = tid & 15, ty = tid >> 4;
    const int m0 = blockIdx.y * 64, n0 = blockIdx.x * 64;
    const int lr = tid >> 2;        // 0..63
    const int lk = (tid & 3) * 4;   // 0,4,8,12

    float acc[4][4];
#pragma unroll
    for (int i = 0; i < 4; i++)
#pragma unroll
        for (int j = 0; j < 4; j++) acc[i][j] = 0.f;

    const float* Aptr = A + (size_t)(m0 + lr) * K + lk;
    const int brow = n0 + lr;
    const float* Bptr = B + (size_t)brow * K + lk;
    const bool bok = (brow < N);

    for (int k0 = 0; k0 < K; k0 += 16) {
        float4 av = *(const float4*)(Aptr + k0);
        float4 bv = bok ? *(const float4*)(Bptr + k0) : make_float4(0.f, 0.f, 0.f, 0.f);
        As[lk + 0][lr] = av.x; As[lk + 1][lr] = av.y;
        As[lk + 2][lr] = av.z; As[lk + 3][lr] = av.w;
        Bs[lk + 0][lr] = bv.x; Bs[lk + 1][lr] = bv.y;
        Bs[lk + 2][lr] = bv.z; Bs[lk + 3][lr] = bv.w;
        __syncthreads();
#pragma unroll
        for (int k = 0; k < 16; k++) {
            float4 a4 = *(const float4*)&As[k][ty * 4];
            float4 b4 = *(const float4*)&Bs[k][tx * 4];
            float ar[4] = {a4.x, a4.y, a4.z, a4.w};
            float br[4] = {b4.x, b4.y, b4.z, b4.w};
#pragma unroll
            for (int i = 0; i < 4; i++)
#pragma unroll
                for (int j = 0; j < 4; j++) acc[i][j] = fmaf(ar[i], br[j], acc[i][j]);
        }
        __syncthreads();
    }

#pragma unroll
    for (int i = 0; i < 4; i++) {
        int row = m0 + ty * 4 + i;
        float rs = (EPI == 0) ? rowscale[row] : 1.f;
#pragma unroll
        for (int j = 0; j < 4; j++) {
            int col = n0 + tx * 4 + j;
            if (col < N) {
                float v = acc[i][j];
                if (EPI == 0) {
                    v *= rs;
                } else {
                    v += bias[col];
                    if (EPI == 1) v = v > 0.f ? v : expm1f(v);
                }
                C[(size_t)row * N + col] = v;
            }
        }
    }
}

// ---------------- launch ----------------
extern "C" void kernel_launch(void* const* d_in, const int* in_sizes, int n_in,
                              void* d_out, int out_size, void* d_ws, size_t ws_size,
                              hipStream_t stream) {
    const float* img_f    = (const float*)d_in[0];   // (8192,8,512)
    const float* tex_f    = (const float*)d_in[1];   // (8,1000,512)
    const float* fake_cls = (const float*)d_in[2];   // (8,16,512)
    const float* fc_w     = (const float*)d_in[3];   // (512,512)
    const float* fc_b     = (const float*)d_in[4];   // (512)
    const float* bn1_g    = (const float*)d_in[5];   // (1024)
    const float* bn1_b    = (const float*)d_in[6];
    const float* w1       = (const float*)d_in[7];   // (2048,1024)
    const float* b1       = (const float*)d_in[8];
    const float* bn2_g    = (const float*)d_in[9];   // (2048)
    const float* bn2_b    = (const float*)d_in[10];
    const float* w2       = (const float*)d_in[11];  // (1000,2048)
    const float* b2       = (const float*)d_in[12];
    float* out = (float*)d_out;

    float* ws = (float*)d_ws;
    // offsets in floats
    const size_t OF_TEXN = 0;                       // 4,096,000
    const size_t OF_G    = OF_TEXN + 4096000;       // 65,536
    const size_t OF_FB   = OF_G + 65536;            // 1,024
    const size_t OF_TEXA = OF_FB + 1024;            // 65,536
    const size_t OF_INV  = OF_TEXA + 65536;         // 65,536
    const size_t OF_CP   = OF_INV + 65536;          // 8,388,608
    const size_t OF_W1A  = OF_CP + 8388608;         // 2,097,152
    const size_t OF_B1P  = OF_W1A + 2097152;        // 2,048
    const size_t OF_A1   = OF_B1P + 2048;           // 1,024
    const size_t OF_C1   = OF_A1 + 1024;            // 1,024
    const size_t OF_PS   = OF_C1 + 1024;            // 131,072
    const size_t OF_PQ   = OF_PS + 131072;          // 131,072
    const size_t OF_H    = OF_PQ + 131072;          // 16,777,216
    const size_t OF_W2A  = OF_H + 16777216;         // 2,048,000
    const size_t OF_B2P  = OF_W2A + 2048000;        // 1,024
    const size_t OF_A2   = OF_B2P + 1024;           // 2,048
    const size_t OF_C2   = OF_A2 + 2048;            // 2,048

    float* texn = ws + OF_TEXN;
    float* g    = ws + OF_G;
    float* fb   = ws + OF_FB;
    float* texa = ws + OF_TEXA;
    float* inv  = ws + OF_INV;
    float* cp   = ws + OF_CP;
    float* w1a  = ws + OF_W1A;
    float* b1p  = ws + OF_B1P;
    float* a1   = ws + OF_A1;
    float* c1   = ws + OF_C1;
    float* ps   = ws + OF_PS;
    float* pq   = ws + OF_PQ;
    float* h    = ws + OF_H;
    float* w2a  = ws + OF_W2A;
    float* b2p  = ws + OF_B2P;
    float* a2   = ws + OF_A2;
    float* c2   = ws + OF_C2;

    // attention path (fp32, tiny)
    k_rownorm<<<8000, 256, 0, stream>>>(tex_f, texn);
    k_imgnorm<<<16384, 256, 0, stream>>>(img_f, inv);
    k_g<<<128, 256, 0, stream>>>(fake_cls, fc_w, fc_b, g, fb);
    k_attn<<<128, 256, 0, stream>>>(g, fb, texn, texa);

    // cp' = rowscale * (img_f @ tex_a^T), stored as 65536x128 row-major
    gemm_tt<0><<<dim3(2, 1024), 256, 0, stream>>>(img_f, texa, cp, 65536, 128, 512, inv, nullptr);

    // BN1 stats + fold into w1 (with column permutation)
    k_colstat<<<dim3(4, 64), 256, 0, stream>>>(cp, ps, pq, 1024);
    k_bnfin<true><<<4, 256, 0, stream>>>(ps, pq, bn1_g, bn1_b, a1, c1, 1024);
    k_foldw<true><<<2048, 256, 0, stream>>>(w1, b1, a1, c1, w1a, b1p, 1024);

    // h = elu(cp' @ w1a^T + b1p)
    gemm_tt<1><<<dim3(32, 128), 256, 0, stream>>>(cp, w1a, h, 8192, 2048, 1024, nullptr, b1p);

    // BN2 stats + fold into w2
    k_colstat<<<dim3(8, 64), 256, 0, stream>>>(h, ps, pq, 2048);
    k_bnfin<false><<<8, 256, 0, stream>>>(ps, pq, bn2_g, bn2_b, a2, c2, 2048);
    k_foldw<false><<<1000, 256, 0, stream>>>(w2, b2, a2, c2, w2a, b2p, 2048);

    // out = h @ w2a^T + b2p
    gemm_tt<2><<<dim3(16, 128), 256, 0, stream>>>(h, w2a, out, 8192, 1000, 2048, nullptr, b2p);
}

// Round 2
// 413.302 us; speedup vs baseline: 3.4622x; 3.4622x over previous
//
#include <hip/hip_runtime.h>
#include <math.h>

// B=8192, X=8, C=512, P=8, Y=1000, FAKE=16, F=2048, CLS=1000, IN_DIM=1024, SF=64
//
// Pipeline (bf16 MFMA for all GEMMs, fp32 attention path):
//  texn = rownorm(tex_f)                       [fp32]
//  inv[r] = 64/(||img row||+1e-6)              [fp32]
//  g = fake_cls @ fc_w, fb = fake_cls . fc_b   [fp32]  (kills the pyc,dc einsum)
//  texa = softmax(g . texn^T + fb) @ texn      [fp32 -> bf16]
//  cp'  = (inv*img) @ texa^T                   [MFMA, A reg-staged fp32->bf16, out bf16,
//                                               permuted cols col'=x*128+p*16+d]
//  BN1 stats on cp' -> fold into w1 (perm)     [bf16 weights]
//  h = elu(cp' @ w1a^T + b1p)                  [MFMA, out bf16]
//  BN2 stats on h -> fold into w2 (pad 1024)   [bf16 weights]
//  out = h @ w2a^T + b2p                       [MFMA, out fp32]

typedef __attribute__((ext_vector_type(8))) short bf16x8;
typedef __attribute__((ext_vector_type(4))) float f32x4;

__device__ __forceinline__ float waveSum(float v) {
#pragma unroll
    for (int o = 32; o > 0; o >>= 1) v += __shfl_xor(v, o);
    return v;
}
__device__ __forceinline__ unsigned short f2bf(float x) {
    union { float f; unsigned u; } v; v.f = x;
    unsigned r = v.u + 0x7FFFu + ((v.u >> 16) & 1u);
    return (unsigned short)(r >> 16);
}
__device__ __forceinline__ float bf2f(unsigned short h) {
    union { unsigned u; float f; } v; v.u = ((unsigned)h) << 16; return v.f;
}
__device__ __forceinline__ void gload16(const void* g, const void* l) {
    __builtin_amdgcn_global_load_lds((const __attribute__((address_space(1))) void*)g,
                                     (__attribute__((address_space(3))) void*)l, 16, 0, 0);
}

// ---------- tex_n = tex_f / (||row||+1e-6) * 64 (fp32) ----------
__global__ __launch_bounds__(256) void k_rownorm(const float* __restrict__ in,
                                                 float* __restrict__ out) {
    int row = blockIdx.x, t = threadIdx.x;
    const float* r = in + (size_t)row * 512;
    float2 v = *(const float2*)(r + t * 2);
    float ss = v.x * v.x + v.y * v.y;
    ss = waveSum(ss);
    __shared__ float sred[4];
    if ((t & 63) == 0) sred[t >> 6] = ss;
    __syncthreads();
    float tot = sred[0] + sred[1] + sred[2] + sred[3];
    float sc = 64.f / (sqrtf(tot) + 1e-6f);
    *(float2*)(out + (size_t)row * 512 + t * 2) = make_float2(v.x * sc, v.y * sc);
}

// ---------- inv[r] = 64/(||img row r||+1e-6); 1 wave per row ----------
__global__ __launch_bounds__(256) void k_imgnorm(const float* __restrict__ in,
                                                 float* __restrict__ inv) {
    int row = blockIdx.x * 4 + (threadIdx.x >> 6);
    int lane = threadIdx.x & 63;
    const float* r = in + (size_t)row * 512 + lane * 8;
    float4 a = *(const float4*)r;
    float4 b = *(const float4*)(r + 4);
    float ss = a.x*a.x + a.y*a.y + a.z*a.z + a.w*a.w
             + b.x*b.x + b.y*b.y + b.z*b.z + b.w*b.w;
    ss = waveSum(ss);
    if (lane == 0) inv[row] = 64.f / (sqrtf(ss) + 1e-6f);
}

// ---------- g[bid,e] = sum_d fcls[bid,d]*fc_w[d,e]; fb[bid] = fcls . fc_b ----------
__global__ __launch_bounds__(256) void k_g(const float* __restrict__ fake_cls,
                                           const float* __restrict__ fc_w,
                                           const float* __restrict__ fc_b,
                                           float* __restrict__ g, float* __restrict__ fb) {
    int bid = blockIdx.x, t = threadIdx.x;
    __shared__ float fcls[512];
    __shared__ float sred[4];
    fcls[t]       = fake_cls[bid * 512 + t];
    fcls[t + 256] = fake_cls[bid * 512 + t + 256];
    __syncthreads();
    float a0 = 0.f, a1 = 0.f;
    for (int d = 0; d < 512; ++d) {
        float fv = fcls[d];
        a0 = fmaf(fv, fc_w[d * 512 + t], a0);
        a1 = fmaf(fv, fc_w[d * 512 + t + 256], a1);
    }
    g[bid * 512 + t]       = a0;
    g[bid * 512 + t + 256] = a1;
    float partial = fcls[t] * fc_b[t] + fcls[t + 256] * fc_b[t + 256];
    partial = waveSum(partial);
    if ((t & 63) == 0) sred[t >> 6] = partial;
    __syncthreads();
    if (t == 0) fb[bid] = sred[0] + sred[1] + sred[2] + sred[3];
}

// ---------- attention: logits -> softmax -> texa[bid,:] (bf16 out) ----------
__global__ __launch_bounds__(256) void k_attn(const float* __restrict__ g,
                                              const float* __restrict__ fb,
                                              const float* __restrict__ texn,
                                              unsigned short* __restrict__ texa) {
    int bid = blockIdx.x;         // p*16 + fake_idx
    int p = bid >> 4;
    int t = threadIdx.x, lane = t & 63, wid = t >> 6;
    __shared__ float gsh[512];
    __shared__ float logits[1000];
    __shared__ float sred[4];
    gsh[t]       = g[bid * 512 + t];
    gsh[t + 256] = g[bid * 512 + t + 256];
    float fbv = fb[bid];
    __syncthreads();
    const float* tn = texn + (size_t)p * 1000 * 512;
    float4 ga = *(const float4*)&gsh[lane * 8];
    float4 gb = *(const float4*)&gsh[lane * 8 + 4];
    for (int y = wid; y < 1000; y += 4) {
        const float* tr = tn + (size_t)y * 512 + lane * 8;
        float4 va = *(const float4*)tr;
        float4 vb = *(const float4*)(tr + 4);
        float s = va.x*ga.x + va.y*ga.y + va.z*ga.z + va.w*ga.w
                + vb.x*gb.x + vb.y*gb.y + vb.z*gb.z + vb.w*gb.w;
        s = waveSum(s);
        if (lane == 0) logits[y] = s + fbv;
    }
    __syncthreads();
    float m = -3.0e38f;
    for (int y = t; y < 1000; y += 256) m = fmaxf(m, logits[y]);
#pragma unroll
    for (int o = 32; o > 0; o >>= 1) m = fmaxf(m, __shfl_xor(m, o));
    if (lane == 0) sred[wid] = m;
    __syncthreads();
    m = fmaxf(fmaxf(sred[0], sred[1]), fmaxf(sred[2], sred[3]));
    __syncthreads();
    float ssum = 0.f;
    for (int y = t; y < 1000; y += 256) {
        float e = expf(logits[y] - m);
        logits[y] = e;
        ssum += e;
    }
    ssum = waveSum(ssum);
    if (lane == 0) sred[wid] = ssum;
    __syncthreads();
    float invd = 1.f / (sred[0] + sred[1] + sred[2] + sred[3]);
    float acc0 = 0.f, acc1 = 0.f;
    for (int y = 0; y < 1000; ++y) {
        float w = logits[y];
        const float* tr = tn + (size_t)y * 512;
        acc0 = fmaf(w, tr[t], acc0);
        acc1 = fmaf(w, tr[t + 256], acc1);
    }
    texa[bid * 512 + t]       = f2bf(acc0 * invd);
    texa[bid * 512 + t + 256] = f2bf(acc1 * invd);
}

// ---------- column stats over bf16 matrix: 128 rows per y-block ----------
__global__ __launch_bounds__(256) void k_colstat_bf(const unsigned short* __restrict__ src,
                                                    float* __restrict__ ps,
                                                    float* __restrict__ pq, int ncols) {
    int col = blockIdx.x * 256 + threadIdx.x;
    int r0 = blockIdx.y * 128;
    const unsigned short* p = src + (size_t)r0 * ncols + col;
    float s = 0.f, q = 0.f;
    for (int r = 0; r < 128; ++r) {
        float v = bf2f(p[(size_t)r * ncols]);
        s += v;
        q = fmaf(v, v, q);
    }
    ps[(size_t)blockIdx.y * ncols + col] = s;
    pq[(size_t)blockIdx.y * ncols + col] = q;
}

// ---------- finalize BN scale/shift; PERM maps permuted col' -> true j ----------
template <bool PERM>
__global__ __launch_bounds__(256) void k_bnfin(const float* __restrict__ ps,
                                               const float* __restrict__ pq,
                                               const float* __restrict__ gam,
                                               const float* __restrict__ bet,
                                               float* __restrict__ a, float* __restrict__ c,
                                               int ncols) {
    int col = blockIdx.x * 256 + threadIdx.x;
    float S = 0.f, Q = 0.f;
    for (int i = 0; i < 64; ++i) {
        S += ps[(size_t)i * ncols + col];
        Q += pq[(size_t)i * ncols + col];
    }
    float mean = S * (1.f / 8192.f);
    float var = Q * (1.f / 8192.f) - mean * mean;
    int j = col;
    if (PERM) {
        int x = col >> 7, jj = col & 127, pp = jj >> 4, d = jj & 15;
        j = (pp << 7) + (x << 4) + d;
    }
    float av = gam[j] * rsqrtf(var + 1e-5f);
    a[col] = av;
    c[col] = bet[j] - mean * av;
}

// ---------- fold BN into weights -> bf16: Wout[f,col]=W[f,j]*a; bout=bin+W.c ----------
template <bool PERM>
__global__ __launch_bounds__(256) void k_foldw_bf(const float* __restrict__ W,
                                                  const float* __restrict__ bin,
                                                  const float* __restrict__ a,
                                                  const float* __restrict__ c,
                                                  unsigned short* __restrict__ Wout,
                                                  float* __restrict__ bout,
                                                  int Kdim, int nvalid) {
    int f = blockIdx.x, t = threadIdx.x;
    unsigned short* wo = Wout + (size_t)f * Kdim;
    if (f >= nvalid) {   // zero-pad tail rows (w2: 1000..1023)
        for (int col = t; col < Kdim; col += 256) wo[col] = 0;
        if (t == 0) bout[f] = 0.f;
        return;
    }
    const float* wr = W + (size_t)f * Kdim;
    float partial = 0.f;
    for (int col = t; col < Kdim; col += 256) {
        int j = col;
        if (PERM) {
            int x = col >> 7, jj = col & 127, pp = jj >> 4, d = jj & 15;
            j = (pp << 7) + (x << 4) + d;
        }
        float wv = wr[j];
        wo[col] = f2bf(wv * a[col]);
        partial = fmaf(wv, c[col], partial);
    }
    partial = waveSum(partial);
    __shared__ float sred[4];
    if ((t & 63) == 0) sred[t >> 6] = partial;
    __syncthreads();
    if (t == 0) bout[f] = bin[f] + sred[0] + sred[1] + sred[2] + sred[3];
}

// ---------- MFMA GEMM: C[M,N] = A[M,K] @ B[N,K]^T ----------
// 128x128 tile, BK=64, 4 waves (each 64x64 = 4x4 frags of 16x16x32 bf16).
// LDS XOR-swizzled (16B granule, bit pattern (row&7)<<4 bytes) via pre-swizzled
// global source for the global_load_lds path, direct swizzled ds_write for the
// reg-staged fp32 A path (rule #21: both-sides-or-neither).
// EPI 0: store bf16           (cp;  A is fp32 scaled by rowscale[row])
// EPI 1: store bf16 elu(x+b)  (h)
// EPI 2: store fp32 x+b, col<N guarded (out)
template <int EPI, bool A_F32>
__global__ __launch_bounds__(256) void gemm_mfma(const void* __restrict__ Av,
                                                 const unsigned short* __restrict__ B,
                                                 void* __restrict__ Cv, int M, int N, int K,
                                                 const float* __restrict__ rowscale,
                                                 const float* __restrict__ bias) {
    __shared__ unsigned short Asl[128 * 64];
    __shared__ unsigned short Bsl[128 * 64];
    const int tid = threadIdx.x;
    const int lane = tid & 63, wid = tid >> 6;
    const int wr = wid >> 1, wc = wid & 1;
    const int m0 = blockIdx.y * 128, n0 = blockIdx.x * 128;

    f32x4 acc[4][4];
#pragma unroll
    for (int i = 0; i < 4; ++i)
#pragma unroll
        for (int j = 0; j < 4; ++j) acc[i][j] = {0.f, 0.f, 0.f, 0.f};

    const int swz = ((lane & 7) ^ (lane >> 3)) * 8;  // source k-elem pre-swizzle
    const int lrow = lane & 15, lkh = lane >> 4;
    const float* Af = (const float*)Av;
    const unsigned short* Ab = (const unsigned short*)Av;

    for (int k0 = 0; k0 < K; k0 += 64) {
        if (A_F32) {
            // reg-stage: load fp32, scale by rowscale, convert, swizzled ds_write
#pragma unroll
            for (int r = 0; r < 4; ++r) {
                int row = r * 32 + (tid >> 3);
                int kk = (tid & 7) * 8;
                const float* src = Af + (size_t)(m0 + row) * K + k0 + kk;
                float4 p0 = *(const float4*)src;
                float4 p1 = *(const float4*)(src + 4);
                float sc = rowscale[m0 + row];
                bf16x8 v;
                v[0] = (short)f2bf(p0.x * sc); v[1] = (short)f2bf(p0.y * sc);
                v[2] = (short)f2bf(p0.z * sc); v[3] = (short)f2bf(p0.w * sc);
                v[4] = (short)f2bf(p1.x * sc); v[5] = (short)f2bf(p1.y * sc);
                v[6] = (short)f2bf(p1.z * sc); v[7] = (short)f2bf(p1.w * sc);
                *(bf16x8*)&Asl[row * 64 + (kk ^ ((row & 7) << 3))] = v;
            }
        } else {
#pragma unroll
            for (int r = 0; r < 4; ++r) {
                int row = r * 32 + wid * 8 + (lane >> 3);
                gload16(Ab + (size_t)(m0 + row) * K + k0 + swz,
                        Asl + r * 2048 + wid * 512);
            }
        }
#pragma unroll
        for (int r = 0; r < 4; ++r) {
            int row = r * 32 + wid * 8 + (lane >> 3);
            gload16(B + (size_t)(n0 + row) * K + k0 + swz,
                    Bsl + r * 2048 + wid * 512);
        }
        __syncthreads();
#pragma unroll
        for (int kk = 0; kk < 2; ++kk) {
            bf16x8 af[4], bfr[4];
#pragma unroll
            for (int m = 0; m < 4; ++m) {
                int row = wr * 64 + m * 16 + lrow;
                af[m] = *(const bf16x8*)&Asl[row * 64 + ((kk * 32 + lkh * 8) ^ ((row & 7) << 3))];
            }
#pragma unroll
            for (int n = 0; n < 4; ++n) {
                int row = wc * 64 + n * 16 + lrow;
                bfr[n] = *(const bf16x8*)&Bsl[row * 64 + ((kk * 32 + lkh * 8) ^ ((row & 7) << 3))];
            }
#pragma unroll
            for (int m = 0; m < 4; ++m)
#pragma unroll
                for (int n = 0; n < 4; ++n)
                    acc[m][n] = __builtin_amdgcn_mfma_f32_16x16x32_bf16(af[m], bfr[n], acc[m][n], 0, 0, 0);
        }
        __syncthreads();
    }

    // epilogue — C/D layout: col = lane&15, row = (lane>>4)*4 + reg  [m89]
    const int colbase = n0 + wc * 64 + lrow;
    float bv[4];
    if (EPI >= 1) {
#pragma unroll
        for (int n = 0; n < 4; ++n) bv[n] = bias[colbase + n * 16];
    }
    if (EPI == 0) {
        unsigned short* C = (unsigned short*)Cv;
#pragma unroll
        for (int m = 0; m < 4; ++m) {
            int row = m0 + wr * 64 + m * 16 + lkh * 4;
#pragma unroll
            for (int r = 0; r < 4; ++r)
#pragma unroll
                for (int n = 0; n < 4; ++n)
                    C[(size_t)(row + r) * N + colbase + n * 16] = f2bf(acc[m][n][r]);
        }
    } else if (EPI == 1) {
        unsigned short* C = (unsigned short*)Cv;
#pragma unroll
        for (int m = 0; m < 4; ++m) {
            int row = m0 + wr * 64 + m * 16 + lkh * 4;
#pragma unroll
            for (int r = 0; r < 4; ++r)
#pragma unroll
                for (int n = 0; n < 4; ++n) {
                    float v = acc[m][n][r] + bv[n];
                    v = v > 0.f ? v : expm1f(v);
                    C[(size_t)(row + r) * N + colbase + n * 16] = f2bf(v);
                }
        }
    } else {
        float* C = (float*)Cv;
#pragma unroll
        for (int m = 0; m < 4; ++m) {
            int row = m0 + wr * 64 + m * 16 + lkh * 4;
#pragma unroll
            for (int r = 0; r < 4; ++r)
#pragma unroll
                for (int n = 0; n < 4; ++n) {
                    int col = colbase + n * 16;
                    if (col < N) C[(size_t)(row + r) * N + col] = acc[m][n][r] + bv[n];
                }
        }
    }
}

// ---------------- launch ----------------
extern "C" void kernel_launch(void* const* d_in, const int* in_sizes, int n_in,
                              void* d_out, int out_size, void* d_ws, size_t ws_size,
                              hipStream_t stream) {
    const float* img_f    = (const float*)d_in[0];   // (8192,8,512)
    const float* tex_f    = (const float*)d_in[1];   // (8,1000,512)
    const float* fake_cls = (const float*)d_in[2];   // (8,16,512)
    const float* fc_w     = (const float*)d_in[3];   // (512,512)
    const float* fc_b     = (const float*)d_in[4];   // (512)
    const float* bn1_g    = (const float*)d_in[5];   // (1024)
    const float* bn1_b    = (const float*)d_in[6];
    const float* w1       = (const float*)d_in[7];   // (2048,1024)
    const float* b1       = (const float*)d_in[8];
    const float* bn2_g    = (const float*)d_in[9];   // (2048)
    const float* bn2_b    = (const float*)d_in[10];
    const float* w2       = (const float*)d_in[11];  // (1000,2048)
    const float* b2       = (const float*)d_in[12];
    float* out = (float*)d_out;

    char* w = (char*)d_ws;   // byte offsets, all 256-aligned; total ~77 MB
    float*          texn = (float*)(w);                      // 16,384,000
    float*          g    = (float*)(w + 16384000);           //    262,144
    float*          fb   = (float*)(w + 16646144);           //        512
    unsigned short* texa = (unsigned short*)(w + 16646656);  //    131,072
    float*          inv  = (float*)(w + 16777728);           //    262,144
    unsigned short* cp   = (unsigned short*)(w + 17039872);  // 16,777,216
    unsigned short* w1a  = (unsigned short*)(w + 33817088);  //  4,194,304
    float*          b1p  = (float*)(w + 38011392);           //      8,192
    float*          a1   = (float*)(w + 38019584);           //      4,096
    float*          c1   = (float*)(w + 38023680);           //      4,096
    float*          ps   = (float*)(w + 38027776);           //    524,288
    float*          pq   = (float*)(w + 38552064);           //    524,288
    unsigned short* h    = (unsigned short*)(w + 39076352);  // 33,554,432
    unsigned short* w2a  = (unsigned short*)(w + 72630784);  //  4,194,304
    float*          b2p  = (float*)(w + 76825088);           //      4,096
    float*          a2   = (float*)(w + 76829184);           //      8,192
    float*          c2   = (float*)(w + 76837376);           //      8,192

    // attention path (fp32, tiny)
    k_rownorm<<<8000, 256, 0, stream>>>(tex_f, texn);
    k_imgnorm<<<16384, 256, 0, stream>>>(img_f, inv);
    k_g<<<128, 256, 0, stream>>>(fake_cls, fc_w, fc_b, g, fb);
    k_attn<<<128, 256, 0, stream>>>(g, fb, texn, texa);

    // cp' = (inv * img) @ texa^T  -> bf16, permuted cols (65536 x 128)
    gemm_mfma<0, true><<<dim3(1, 512), 256, 0, stream>>>(
        img_f, texa, cp, 65536, 128, 512, inv, nullptr);

    // BN1 stats + fold into w1 (column permutation)
    k_colstat_bf<<<dim3(4, 64), 256, 0, stream>>>(cp, ps, pq, 1024);
    k_bnfin<true><<<4, 256, 0, stream>>>(ps, pq, bn1_g, bn1_b, a1, c1, 1024);
    k_foldw_bf<true><<<2048, 256, 0, stream>>>(w1, b1, a1, c1, w1a, b1p, 1024, 2048);

    // h = elu(cp' @ w1a^T + b1p) -> bf16
    gemm_mfma<1, false><<<dim3(16, 64), 256, 0, stream>>>(
        cp, w1a, h, 8192, 2048, 1024, nullptr, b1p);

    // BN2 stats + fold into w2 (pad rows to 1024 with zeros)
    k_colstat_bf<<<dim3(8, 64), 256, 0, stream>>>(h, ps, pq, 2048);
    k_bnfin<false><<<8, 256, 0, stream>>>(ps, pq, bn2_g, bn2_b, a2, c2, 2048);
    k_foldw_bf<false><<<1024, 256, 0, stream>>>(w2, b2, a2, c2, w2a, b2p, 2048, 1000);

    // out = h @ w2a^T + b2p -> fp32
    gemm_mfma<2, false><<<dim3(8, 64), 256, 0, stream>>>(
        h, w2a, out, 8192, 1000, 2048, nullptr, b2p);
}

// Round 3
// 277.059 us; speedup vs baseline: 5.1647x; 1.4917x over previous
//
#include <hip/hip_runtime.h>
#include <math.h>

// B=8192, X=8, C=512, P=8, Y=1000, FAKE=16, F=2048, CLS=1000, IN_DIM=1024, SF=64
//
// Pipeline:
//  texn = rownorm(tex_f) -> bf16
//  inv[r] = 64/(||img row||+1e-6)
//  g_bf = fake_cls @ fc_w -> bf16             (fc_b shift cancels in softmax)
//  logits[p] = g_bf[p] @ texn[p]^T            [MFMA, EPI3, z=p]
//  attnw = softmax(logits) -> bf16 (padded)
//  texa = attnw @ texn                        (split-y partials + reduce)
//  cp'  = (inv*img) @ texa^T                  [MFMA, A reg-staged fp32->bf16, out bf16,
//                                              permuted cols col'=x*128+p*16+d]
//  BN1 stats -> fold into w1 (perm)           [bf16 weights]
//  h = elu(cp' @ w1a^T + b1p)                 [MFMA, out bf16]
//  BN2 stats -> fold into w2 (pad 1024)       [bf16 weights]
//  out = h @ w2a^T + b2p                      [MFMA, out fp32]

typedef __attribute__((ext_vector_type(8))) short bf16x8;
typedef __attribute__((ext_vector_type(4))) float f32x4;

__device__ __forceinline__ float waveSum(float v) {
#pragma unroll
    for (int o = 32; o > 0; o >>= 1) v += __shfl_xor(v, o);
    return v;
}
__device__ __forceinline__ float waveMax(float v) {
#pragma unroll
    for (int o = 32; o > 0; o >>= 1) v = fmaxf(v, __shfl_xor(v, o));
    return v;
}
__device__ __forceinline__ unsigned short f2bf(float x) {
    union { float f; unsigned u; } v; v.f = x;
    unsigned r = v.u + 0x7FFFu + ((v.u >> 16) & 1u);
    return (unsigned short)(r >> 16);
}
__device__ __forceinline__ float bf2f(unsigned short h) {
    union { unsigned u; float f; } v; v.u = ((unsigned)h) << 16; return v.f;
}
__device__ __forceinline__ void gload16(const void* g, const void* l) {
    __builtin_amdgcn_global_load_lds((const __attribute__((address_space(1))) void*)g,
                                     (__attribute__((address_space(3))) void*)l, 16, 0, 0);
}
__device__ __forceinline__ int xcd_swz(int d, int n) {
    int q = n >> 3;                     // all gemm grids are %8==0
    return (d & 7) * q + (d >> 3);
}

// ---------- texn = tex_f/(||row||+1e-6)*64 -> bf16 ----------
__global__ __launch_bounds__(256) void k_rownorm_bf(const float* __restrict__ in,
                                                    unsigned short* __restrict__ out) {
    int row = blockIdx.x, t = threadIdx.x;
    const float* r = in + (size_t)row * 512;
    float2 v = *(const float2*)(r + t * 2);
    float ss = v.x * v.x + v.y * v.y;
    ss = waveSum(ss);
    __shared__ float sred[4];
    if ((t & 63) == 0) sred[t >> 6] = ss;
    __syncthreads();
    float tot = sred[0] + sred[1] + sred[2] + sred[3];
    float sc = 64.f / (sqrtf(tot) + 1e-6f);
    unsigned u = (unsigned)f2bf(v.x * sc) | ((unsigned)f2bf(v.y * sc) << 16);
    *(unsigned*)(out + (size_t)row * 512 + t * 2) = u;
}

// ---------- inv[r] = 64/(||img row r||+1e-6); 1 wave per row ----------
__global__ __launch_bounds__(256) void k_imgnorm(const float* __restrict__ in,
                                                 float* __restrict__ inv) {
    int row = blockIdx.x * 4 + (threadIdx.x >> 6);
    int lane = threadIdx.x & 63;
    const float* r = in + (size_t)row * 512 + lane * 8;
    float4 a = *(const float4*)r;
    float4 b = *(const float4*)(r + 4);
    float ss = a.x*a.x + a.y*a.y + a.z*a.z + a.w*a.w
             + b.x*b.x + b.y*b.y + b.z*b.z + b.w*b.w;
    ss = waveSum(ss);
    if (lane == 0) inv[row] = 64.f / (sqrtf(ss) + 1e-6f);
}

// ---------- g_bf[bid,e] = sum_d fcls[bid,d]*fc_w[d,e] -> bf16 ----------
__global__ __launch_bounds__(256) void k_gbf(const float* __restrict__ fake_cls,
                                             const float* __restrict__ fc_w,
                                             unsigned short* __restrict__ g_bf) {
    int bid = blockIdx.x, t = threadIdx.x;
    __shared__ float fcls[512];
    fcls[t]       = fake_cls[bid * 512 + t];
    fcls[t + 256] = fake_cls[bid * 512 + t + 256];
    __syncthreads();
    float a0 = 0.f, a1 = 0.f;
    for (int d = 0; d < 512; ++d) {
        float fv = fcls[d];
        a0 = fmaf(fv, fc_w[d * 512 + t], a0);
        a1 = fmaf(fv, fc_w[d * 512 + t + 256], a1);
    }
    g_bf[bid * 512 + t]       = f2bf(a0);
    g_bf[bid * 512 + t + 256] = f2bf(a1);
}

// ---------- softmax over 1000 logits -> normalized bf16 weights (1024 padded) ----------
__global__ __launch_bounds__(256) void k_softmax(const float* __restrict__ logits,
                                                 unsigned short* __restrict__ attnw) {
    int row = blockIdx.x, t = threadIdx.x, lane = t & 63, wid = t >> 6;
    __shared__ float sred[4];
    float v[4];
#pragma unroll
    for (int i = 0; i < 4; ++i) {
        int y = t + i * 256;
        v[i] = (y < 1000) ? logits[(size_t)row * 1000 + y] : -3.0e38f;
    }
    float m = fmaxf(fmaxf(v[0], v[1]), fmaxf(v[2], v[3]));
    m = waveMax(m);
    if (lane == 0) sred[wid] = m;
    __syncthreads();
    m = fmaxf(fmaxf(sred[0], sred[1]), fmaxf(sred[2], sred[3]));
    __syncthreads();
    float s = 0.f;
#pragma unroll
    for (int i = 0; i < 4; ++i) {
        int y = t + i * 256;
        float e = (y < 1000) ? expf(v[i] - m) : 0.f;
        v[i] = e;
        s += e;
    }
    s = waveSum(s);
    if (lane == 0) sred[wid] = s;
    __syncthreads();
    float inv = 1.f / (sred[0] + sred[1] + sred[2] + sred[3]);
#pragma unroll
    for (int i = 0; i < 4; ++i)
        attnw[(size_t)row * 1024 + t + i * 256] = f2bf(v[i] * inv);
}

// ---------- texa partials: block (yt, p) accumulates 16x512 over 125 y ----------
__global__ __launch_bounds__(256) void k_wsum(const unsigned short* __restrict__ attnw,
                                              const unsigned short* __restrict__ texn,
                                              float* __restrict__ part) {
    int yt = blockIdx.x, p = blockIdx.y, t = threadIdx.x;
    __shared__ float wl[16][125];
    for (int idx = t; idx < 16 * 125; idx += 256) {
        int x = idx / 125, y = idx % 125;
        wl[x][y] = bf2f(attnw[(size_t)(p * 16 + x) * 1024 + yt * 125 + y]);
    }
    __syncthreads();
    int c0 = t * 2;
    const unsigned short* tp = texn + ((size_t)p * 1000 + yt * 125) * 512 + c0;
    float a0[16], a1[16];
#pragma unroll
    for (int x = 0; x < 16; ++x) { a0[x] = 0.f; a1[x] = 0.f; }
    for (int y = 0; y < 125; ++y) {
        unsigned u = *(const unsigned*)(tp + (size_t)y * 512);
        float lo = bf2f((unsigned short)(u & 0xffff));
        float hi = bf2f((unsigned short)(u >> 16));
#pragma unroll
        for (int x = 0; x < 16; ++x) {
            float w = wl[x][y];
            a0[x] = fmaf(w, lo, a0[x]);
            a1[x] = fmaf(w, hi, a1[x]);
        }
    }
#pragma unroll
    for (int x = 0; x < 16; ++x) {
        float* dst = part + ((size_t)((p * 8 + yt) * 16 + x)) * 512 + c0;
        dst[0] = a0[x];
        dst[1] = a1[x];
    }
}

// ---------- reduce 8 y-partials -> texa bf16 ----------
__global__ __launch_bounds__(256) void k_texa_red(const float* __restrict__ part,
                                                  unsigned short* __restrict__ texa) {
    int row = blockIdx.x, t = threadIdx.x;      // row = p*16 + x
    int p = row >> 4, x = row & 15;
    int c = t * 2;
    float s0 = 0.f, s1 = 0.f;
#pragma unroll
    for (int yt = 0; yt < 8; ++yt) {
        const float* src = part + ((size_t)((p * 8 + yt) * 16 + x)) * 512 + c;
        s0 += src[0];
        s1 += src[1];
    }
    unsigned u = (unsigned)f2bf(s0) | ((unsigned)f2bf(s1) << 16);
    *(unsigned*)(texa + (size_t)row * 512 + c) = u;
}

// ---------- column stats over bf16 matrix: 128 rows per y-block ----------
__global__ __launch_bounds__(256) void k_colstat_bf(const unsigned short* __restrict__ src,
                                                    float* __restrict__ ps,
                                                    float* __restrict__ pq, int ncols) {
    int col = blockIdx.x * 256 + threadIdx.x;
    int r0 = blockIdx.y * 128;
    const unsigned short* p = src + (size_t)r0 * ncols + col;
    float s = 0.f, q = 0.f;
    for (int r = 0; r < 128; ++r) {
        float v = bf2f(p[(size_t)r * ncols]);
        s += v;
        q = fmaf(v, v, q);
    }
    ps[(size_t)blockIdx.y * ncols + col] = s;
    pq[(size_t)blockIdx.y * ncols + col] = q;
}

// ---------- finalize BN scale/shift; PERM maps permuted col' -> true j ----------
template <bool PERM>
__global__ __launch_bounds__(256) void k_bnfin(const float* __restrict__ ps,
                                               const float* __restrict__ pq,
                                               const float* __restrict__ gam,
                                               const float* __restrict__ bet,
                                               float* __restrict__ a, float* __restrict__ c,
                                               int ncols) {
    int col = blockIdx.x * 256 + threadIdx.x;
    float S = 0.f, Q = 0.f;
    for (int i = 0; i < 64; ++i) {
        S += ps[(size_t)i * ncols + col];
        Q += pq[(size_t)i * ncols + col];
    }
    float mean = S * (1.f / 8192.f);
    float var = Q * (1.f / 8192.f) - mean * mean;
    int j = col;
    if (PERM) {
        int x = col >> 7, jj = col & 127, pp = jj >> 4, d = jj & 15;
        j = (pp << 7) + (x << 4) + d;
    }
    float av = gam[j] * rsqrtf(var + 1e-5f);
    a[col] = av;
    c[col] = bet[j] - mean * av;
}

// ---------- fold BN into weights -> bf16 ----------
template <bool PERM>
__global__ __launch_bounds__(256) void k_foldw_bf(const float* __restrict__ W,
                                                  const float* __restrict__ bin,
                                                  const float* __restrict__ a,
                                                  const float* __restrict__ c,
                                                  unsigned short* __restrict__ Wout,
                                                  float* __restrict__ bout,
                                                  int Kdim, int nvalid) {
    int f = blockIdx.x, t = threadIdx.x;
    unsigned short* wo = Wout + (size_t)f * Kdim;
    if (f >= nvalid) {
        for (int col = t; col < Kdim; col += 256) wo[col] = 0;
        if (t == 0) bout[f] = 0.f;
        return;
    }
    const float* wr = W + (size_t)f * Kdim;
    float partial = 0.f;
    for (int col = t; col < Kdim; col += 256) {
        int j = col;
        if (PERM) {
            int x = col >> 7, jj = col & 127, pp = jj >> 4, d = jj & 15;
            j = (pp << 7) + (x << 4) + d;
        }
        float wv = wr[j];
        wo[col] = f2bf(wv * a[col]);
        partial = fmaf(wv, c[col], partial);
    }
    partial = waveSum(partial);
    __shared__ float sred[4];
    if ((t & 63) == 0) sred[t >> 6] = partial;
    __syncthreads();
    if (t == 0) bout[f] = bin[f] + sred[0] + sred[1] + sred[2] + sred[3];
}

// ---------- MFMA GEMM: C = A @ B^T, 128x128 tile, BK=64, 4 waves ----------
// Grid: x = flattened (ntm*ntn) with XCD swizzle, y = z (batched slabs).
// EPI 0: bf16 store                  (cp;  A fp32 reg-staged, scaled by rowscale)
// EPI 1: bf16 elu(x+bias)            (h)
// EPI 2: fp32 x+bias, col<nvalid     (out)
// EPI 3: fp32 x, col<nvalid, row<16  (logits, batched over z=p)
template <int EPI, bool A_F32>
__global__ __launch_bounds__(256) void gemm_mfma(const void* __restrict__ Av,
                                                 const unsigned short* __restrict__ Bv,
                                                 void* __restrict__ Cv, int K,
                                                 int ntn, int ldc, int nvalid,
                                                 const float* __restrict__ rowscale,
                                                 const float* __restrict__ bias,
                                                 int aZ, int bZ, int cZ) {
    __shared__ unsigned short Asl[128 * 64];
    __shared__ unsigned short Bsl[128 * 64];
    const int tid = threadIdx.x;
    const int lane = tid & 63, wid = tid >> 6;
    const int wr = wid >> 1, wc = wid & 1;
    const int wg = xcd_swz(blockIdx.x, gridDim.x);
    const int m0 = (wg / ntn) * 128, n0 = (wg % ntn) * 128;
    const int z = blockIdx.y;

    const float* Af = (const float*)Av;
    const unsigned short* Ab = (const unsigned short*)Av + (size_t)z * aZ;
    const unsigned short* B = Bv + (size_t)z * bZ;

    f32x4 acc[4][4];
#pragma unroll
    for (int i = 0; i < 4; ++i)
#pragma unroll
        for (int j = 0; j < 4; ++j) acc[i][j] = {0.f, 0.f, 0.f, 0.f};

    const int swz = ((lane & 7) ^ (lane >> 3)) * 8;
    const int lrow = lane & 15, lkh = lane >> 4;

    for (int k0 = 0; k0 < K; k0 += 64) {
        if (A_F32) {
#pragma unroll
            for (int r = 0; r < 4; ++r) {
                int row = r * 32 + (tid >> 3);
                int kk = (tid & 7) * 8;
                const float* src = Af + (size_t)(m0 + row) * K + k0 + kk;
                float4 p0 = *(const float4*)src;
                float4 p1 = *(const float4*)(src + 4);
                float sc = rowscale[m0 + row];
                bf16x8 v;
                v[0] = (short)f2bf(p0.x * sc); v[1] = (short)f2bf(p0.y * sc);
                v[2] = (short)f2bf(p0.z * sc); v[3] = (short)f2bf(p0.w * sc);
                v[4] = (short)f2bf(p1.x * sc); v[5] = (short)f2bf(p1.y * sc);
                v[6] = (short)f2bf(p1.z * sc); v[7] = (short)f2bf(p1.w * sc);
                *(bf16x8*)&Asl[row * 64 + (kk ^ ((row & 7) << 3))] = v;
            }
        } else {
#pragma unroll
            for (int r = 0; r < 4; ++r) {
                int row = r * 32 + wid * 8 + (lane >> 3);
                gload16(Ab + (size_t)(m0 + row) * K + k0 + swz,
                        Asl + r * 2048 + wid * 512);
            }
        }
#pragma unroll
        for (int r = 0; r < 4; ++r) {
            int row = r * 32 + wid * 8 + (lane >> 3);
            gload16(B + (size_t)(n0 + row) * K + k0 + swz,
                    Bsl + r * 2048 + wid * 512);
        }
        __syncthreads();
#pragma unroll
        for (int kk = 0; kk < 2; ++kk) {
            bf16x8 af[4], bfr[4];
#pragma unroll
            for (int m = 0; m < 4; ++m) {
                int row = wr * 64 + m * 16 + lrow;
                af[m] = *(const bf16x8*)&Asl[row * 64 + ((kk * 32 + lkh * 8) ^ ((row & 7) << 3))];
            }
#pragma unroll
            for (int n = 0; n < 4; ++n) {
                int row = wc * 64 + n * 16 + lrow;
                bfr[n] = *(const bf16x8*)&Bsl[row * 64 + ((kk * 32 + lkh * 8) ^ ((row & 7) << 3))];
            }
#pragma unroll
            for (int m = 0; m < 4; ++m)
#pragma unroll
                for (int n = 0; n < 4; ++n)
                    acc[m][n] = __builtin_amdgcn_mfma_f32_16x16x32_bf16(af[m], bfr[n], acc[m][n], 0, 0, 0);
        }
        __syncthreads();
    }

    // epilogue — C/D layout: col = lane&15, row = (lane>>4)*4 + reg  [m89]
    const int colbase = n0 + wc * 64 + lrow;
    float bv[4];
    if (EPI == 1 || EPI == 2) {
#pragma unroll
        for (int n = 0; n < 4; ++n) bv[n] = bias[colbase + n * 16];
    }
    if (EPI == 0 || EPI == 1) {
        unsigned short* C = (unsigned short*)Cv;
#pragma unroll
        for (int m = 0; m < 4; ++m) {
            int row = m0 + wr * 64 + m * 16 + lkh * 4;
#pragma unroll
            for (int r = 0; r < 4; ++r)
#pragma unroll
                for (int n = 0; n < 4; ++n) {
                    float v = acc[m][n][r];
                    if (EPI == 1) {
                        v += bv[n];
                        v = v > 0.f ? v : expm1f(v);
                    }
                    C[(size_t)(row + r) * ldc + colbase + n * 16] = f2bf(v);
                }
        }
    } else {
        float* C = (float*)Cv + (size_t)z * cZ;
#pragma unroll
        for (int m = 0; m < 4; ++m) {
            int row = m0 + wr * 64 + m * 16 + lkh * 4;
#pragma unroll
            for (int r = 0; r < 4; ++r) {
                if (EPI == 3 && (row + r) >= 16) continue;
#pragma unroll
                for (int n = 0; n < 4; ++n) {
                    int col = colbase + n * 16;
                    if (col < nvalid) {
                        float v = acc[m][n][r];
                        if (EPI == 2) v += bv[n];
                        C[(size_t)(row + r) * ldc + col] = v;
                    }
                }
            }
        }
    }
}

// ---------------- launch ----------------
extern "C" void kernel_launch(void* const* d_in, const int* in_sizes, int n_in,
                              void* d_out, int out_size, void* d_ws, size_t ws_size,
                              hipStream_t stream) {
    const float* img_f    = (const float*)d_in[0];   // (8192,8,512)
    const float* tex_f    = (const float*)d_in[1];   // (8,1000,512)
    const float* fake_cls = (const float*)d_in[2];   // (8,16,512)
    const float* fc_w     = (const float*)d_in[3];   // (512,512)
    const float* bn1_g    = (const float*)d_in[5];   // (1024)
    const float* bn1_b    = (const float*)d_in[6];
    const float* w1       = (const float*)d_in[7];   // (2048,1024)
    const float* b1       = (const float*)d_in[8];
    const float* bn2_g    = (const float*)d_in[9];   // (2048)
    const float* bn2_b    = (const float*)d_in[10];
    const float* w2       = (const float*)d_in[11];  // (1000,2048)
    const float* b2       = (const float*)d_in[12];
    float* out = (float*)d_out;

    char* w = (char*)d_ws;   // byte offsets; total ~68.4 MB
    unsigned short* texn = (unsigned short*)(w);             // (8000+24 pad)*512*2
    unsigned short* g_bf = (unsigned short*)(w + 8388608);   // 256*512*2 (128 valid + pad)
    float*          logit= (float*)(w + 8650752);            // 128*1000*4
    unsigned short* attnw= (unsigned short*)(w + 9175040);   // 128*1024*2
    float*          part = (float*)(w + 9437184);            // 8*8*16*512*4
    unsigned short* texa = (unsigned short*)(w + 11534336);  // 128*512*2
    float*          inv  = (float*)(w + 11665408);           // 65536*4
    unsigned short* cp   = (unsigned short*)(w + 11927552);  // 8192*1024*2
    unsigned short* w1a  = (unsigned short*)(w + 28704768);  // 2048*1024*2
    float*          b1p  = (float*)(w + 32899072);           // 2048*4
    float*          a1   = (float*)(w + 32907264);
    float*          c1   = (float*)(w + 32911360);
    float*          ps   = (float*)(w + 32915456);           // 64*2048*4
    float*          pq   = (float*)(w + 33439744);
    unsigned short* h    = (unsigned short*)(w + 33964032);  // 8192*2048*2
    unsigned short* w2a  = (unsigned short*)(w + 67518464);  // 1024*2048*2
    float*          b2p  = (float*)(w + 71712768);
    float*          a2   = (float*)(w + 71716864);
    float*          c2   = (float*)(w + 71725056);

    // ---- attention path ----
    k_rownorm_bf<<<8000, 256, 0, stream>>>(tex_f, texn);
    k_imgnorm<<<16384, 256, 0, stream>>>(img_f, inv);
    k_gbf<<<128, 256, 0, stream>>>(fake_cls, fc_w, g_bf);
    // logits[p] = g_bf[p] (16x512, M-padded) @ texn[p]^T  (1000 cols, padded reads)
    gemm_mfma<3, false><<<dim3(8, 8), 256, 0, stream>>>(
        g_bf, texn, logit, 512, 8, 1000, 1000, nullptr, nullptr,
        16 * 512, 1000 * 512, 16 * 1000);
    k_softmax<<<128, 256, 0, stream>>>(logit, attnw);
    k_wsum<<<dim3(8, 8), 256, 0, stream>>>(attnw, texn, part);
    k_texa_red<<<128, 256, 0, stream>>>(part, texa);

    // ---- cp' = (inv*img) @ texa^T -> bf16, permuted cols (65536 x 128) ----
    gemm_mfma<0, true><<<dim3(512, 1), 256, 0, stream>>>(
        img_f, texa, cp, 512, 1, 128, 128, inv, nullptr, 0, 0, 0);

    // ---- BN1 -> fold into w1 (column permutation) ----
    k_colstat_bf<<<dim3(4, 64), 256, 0, stream>>>(cp, ps, pq, 1024);
    k_bnfin<true><<<4, 256, 0, stream>>>(ps, pq, bn1_g, bn1_b, a1, c1, 1024);
    k_foldw_bf<true><<<2048, 256, 0, stream>>>(w1, b1, a1, c1, w1a, b1p, 1024, 2048);

    // ---- h = elu(cp' @ w1a^T + b1p) -> bf16 ----
    gemm_mfma<1, false><<<dim3(1024, 1), 256, 0, stream>>>(
        cp, w1a, h, 1024, 16, 2048, 2048, nullptr, b1p, 0, 0, 0);

    // ---- BN2 -> fold into w2 (pad rows to 1024) ----
    k_colstat_bf<<<dim3(8, 64), 256, 0, stream>>>(h, ps, pq, 2048);
    k_bnfin<false><<<8, 256, 0, stream>>>(ps, pq, bn2_g, bn2_b, a2, c2, 2048);
    k_foldw_bf<false><<<1024, 256, 0, stream>>>(w2, b2, a2, c2, w2a, b2p, 2048, 1000);

    // ---- out = h @ w2a^T + b2p -> fp32 ----
    gemm_mfma<2, false><<<dim3(512, 1), 256, 0, stream>>>(
        h, w2a, out, 2048, 8, 1000, 1000, nullptr, b2p, 0, 0, 0);
}

// Round 4
// 249.677 us; speedup vs baseline: 5.7312x; 1.1097x over previous
//
#include <hip/hip_runtime.h>
#include <math.h>

// B=8192, X=8, C=512, P=8, Y=1000, FAKE=16, F=2048, CLS=1000, IN_DIM=1024, SF=64
//
// Pipeline (12 launches):
//  k_prep:   texn = rownorm(tex_f)->bf16  |  g_bf = fake_cls @ fc_w ->bf16
//  logits[p] = g_bf[p] @ texn[p]^T            [MFMA EPI3, z=p]
//  k_wsum_sm: softmax(logits) fused, partial texa sums (16 y-tiles x 8 p)
//  k_texa_red: reduce -> texa bf16
//  cp' = (img @ texa^T) * inv_row             [MFMA EPI0, A fp32 reg-staged,
//                                              row-norm computed inline, out bf16,
//                                              permuted cols col'=x*128+p*16+d]
//  colstat(cp) -> bnfin1 -> foldw1 (perm)     [bf16 weights]
//  h = elu(cp' @ w1a^T + b1p)                 [MFMA EPI1, col-stats fused -> ps/pq]
//  bnfin2 -> foldw2 (pad 1024)                [bf16 weights]
//  out = h @ w2a^T + b2p                      [MFMA EPI2, fp32]

typedef __attribute__((ext_vector_type(8))) short bf16x8;
typedef __attribute__((ext_vector_type(4))) float f32x4;

__device__ __forceinline__ float waveSum(float v) {
#pragma unroll
    for (int o = 32; o > 0; o >>= 1) v += __shfl_xor(v, o);
    return v;
}
__device__ __forceinline__ float waveMax(float v) {
#pragma unroll
    for (int o = 32; o > 0; o >>= 1) v = fmaxf(v, __shfl_xor(v, o));
    return v;
}
__device__ __forceinline__ unsigned short f2bf(float x) {
    union { float f; unsigned u; } v; v.f = x;
    unsigned r = v.u + 0x7FFFu + ((v.u >> 16) & 1u);
    return (unsigned short)(r >> 16);
}
__device__ __forceinline__ float bf2f(unsigned short h) {
    union { unsigned u; float f; } v; v.u = ((unsigned)h) << 16; return v.f;
}
__device__ __forceinline__ void gload16(const void* g, const void* l) {
    __builtin_amdgcn_global_load_lds((const __attribute__((address_space(1))) void*)g,
                                     (__attribute__((address_space(3))) void*)l, 16, 0, 0);
}
__device__ __forceinline__ int xcd_swz(int d, int n) {
    int q = n >> 3;                     // all gemm grids are %8==0
    return (d & 7) * q + (d >> 3);
}

// ---------- fused: rownorm(tex_f)->texn bf16 (blocks 0..7999), g_bf (8000..8127) ----------
__global__ __launch_bounds__(256) void k_prep(const float* __restrict__ tex_f,
                                              unsigned short* __restrict__ texn,
                                              const float* __restrict__ fake_cls,
                                              const float* __restrict__ fc_w,
                                              unsigned short* __restrict__ g_bf) {
    __shared__ float sred[4];
    __shared__ float fcls[512];
    int bid = blockIdx.x, t = threadIdx.x;
    if (bid < 8000) {
        const float* r = tex_f + (size_t)bid * 512;
        float2 v = *(const float2*)(r + t * 2);
        float ss = v.x * v.x + v.y * v.y;
        ss = waveSum(ss);
        if ((t & 63) == 0) sred[t >> 6] = ss;
        __syncthreads();
        float tot = sred[0] + sred[1] + sred[2] + sred[3];
        float sc = 64.f / (sqrtf(tot) + 1e-6f);
        unsigned u = (unsigned)f2bf(v.x * sc) | ((unsigned)f2bf(v.y * sc) << 16);
        *(unsigned*)(texn + (size_t)bid * 512 + t * 2) = u;
    } else {
        int row = bid - 8000;
        fcls[t]       = fake_cls[row * 512 + t];
        fcls[t + 256] = fake_cls[row * 512 + t + 256];
        __syncthreads();
        float a0 = 0.f, a1 = 0.f;
        for (int d = 0; d < 512; ++d) {
            float fv = fcls[d];
            a0 = fmaf(fv, fc_w[d * 512 + t], a0);
            a1 = fmaf(fv, fc_w[d * 512 + t + 256], a1);
        }
        g_bf[row * 512 + t]       = f2bf(a0);
        g_bf[row * 512 + t + 256] = f2bf(a1);
    }
}

// ---------- wsum with fused softmax: block (yt 0..15, p 0..7) ----------
__global__ __launch_bounds__(256) void k_wsum_sm(const float* __restrict__ logit,
                                                 const unsigned short* __restrict__ texn,
                                                 float* __restrict__ part) {
    int yt = blockIdx.x, p = blockIdx.y, t = threadIdx.x;
    int lane = t & 63, w = t >> 6;
    __shared__ float wl[16][63];
    __shared__ float ms[16], iss[16];
    const int y0 = yt * 63;
    const int ylen = min(63, 1000 - y0);
    // per-row softmax stats (wave w handles rows w*4..w*4+3)
#pragma unroll
    for (int rr = 0; rr < 4; ++rr) {
        int x = w * 4 + rr;
        const float* lr = logit + ((size_t)p * 16 + x) * 1000;
        float m = -3.0e38f;
        for (int y = lane; y < 1000; y += 64) m = fmaxf(m, lr[y]);
        m = waveMax(m);
        float s = 0.f;
        for (int y = lane; y < 1000; y += 64) s += expf(lr[y] - m);
        s = waveSum(s);
        if (lane == 0) { ms[x] = m; iss[x] = 1.f / s; }
    }
    __syncthreads();
    for (int idx = t; idx < 16 * ylen; idx += 256) {
        int x = idx / ylen, y = idx % ylen;
        wl[x][y] = expf(logit[((size_t)p * 16 + x) * 1000 + y0 + y] - ms[x]) * iss[x];
    }
    __syncthreads();
    int c0 = t * 2;
    const unsigned short* tp = texn + ((size_t)p * 1000 + y0) * 512 + c0;
    float a0[16], a1[16];
#pragma unroll
    for (int x = 0; x < 16; ++x) { a0[x] = 0.f; a1[x] = 0.f; }
    for (int y = 0; y < ylen; ++y) {
        unsigned u = *(const unsigned*)(tp + (size_t)y * 512);
        float lo = bf2f((unsigned short)(u & 0xffff));
        float hi = bf2f((unsigned short)(u >> 16));
#pragma unroll
        for (int x = 0; x < 16; ++x) {
            float ww = wl[x][y];
            a0[x] = fmaf(ww, lo, a0[x]);
            a1[x] = fmaf(ww, hi, a1[x]);
        }
    }
#pragma unroll
    for (int x = 0; x < 16; ++x) {
        float* dst = part + ((size_t)((yt * 8 + p) * 16 + x)) * 512 + c0;
        dst[0] = a0[x];
        dst[1] = a1[x];
    }
}

// ---------- reduce 16 y-partials -> texa bf16 ----------
__global__ __launch_bounds__(256) void k_texa_red(const float* __restrict__ part,
                                                  unsigned short* __restrict__ texa) {
    int row = blockIdx.x, t = threadIdx.x;      // row = p*16 + x
    int p = row >> 4, x = row & 15;
    int c = t * 2;
    float s0 = 0.f, s1 = 0.f;
#pragma unroll
    for (int yt = 0; yt < 16; ++yt) {
        const float* src = part + ((size_t)((yt * 8 + p) * 16 + x)) * 512 + c;
        s0 += src[0];
        s1 += src[1];
    }
    unsigned u = (unsigned)f2bf(s0) | ((unsigned)f2bf(s1) << 16);
    *(unsigned*)(texa + (size_t)row * 512 + c) = u;
}

// ---------- column stats over bf16 matrix (cp): 128 rows per y-block ----------
__global__ __launch_bounds__(256) void k_colstat_bf(const unsigned short* __restrict__ src,
                                                    float* __restrict__ ps,
                                                    float* __restrict__ pq, int ncols) {
    int col = blockIdx.x * 256 + threadIdx.x;
    int r0 = blockIdx.y * 128;
    const unsigned short* p = src + (size_t)r0 * ncols + col;
    float s = 0.f, q = 0.f;
    for (int r = 0; r < 128; ++r) {
        float v = bf2f(p[(size_t)r * ncols]);
        s += v;
        q = fmaf(v, v, q);
    }
    ps[(size_t)blockIdx.y * ncols + col] = s;
    pq[(size_t)blockIdx.y * ncols + col] = q;
}

// ---------- finalize BN scale/shift; PERM maps permuted col' -> true j ----------
template <bool PERM>
__global__ __launch_bounds__(256) void k_bnfin(const float* __restrict__ ps,
                                               const float* __restrict__ pq,
                                               const float* __restrict__ gam,
                                               const float* __restrict__ bet,
                                               float* __restrict__ a, float* __restrict__ c,
                                               int ncols) {
    int col = blockIdx.x * 256 + threadIdx.x;
    float S = 0.f, Q = 0.f;
    for (int i = 0; i < 64; ++i) {
        S += ps[(size_t)i * ncols + col];
        Q += pq[(size_t)i * ncols + col];
    }
    float mean = S * (1.f / 8192.f);
    float var = Q * (1.f / 8192.f) - mean * mean;
    int j = col;
    if (PERM) {
        int x = col >> 7, jj = col & 127, pp = jj >> 4, d = jj & 15;
        j = (pp << 7) + (x << 4) + d;
    }
    float av = gam[j] * rsqrtf(var + 1e-5f);
    a[col] = av;
    c[col] = bet[j] - mean * av;
}

// ---------- fold BN into weights -> bf16 ----------
template <bool PERM>
__global__ __launch_bounds__(256) void k_foldw_bf(const float* __restrict__ W,
                                                  const float* __restrict__ bin,
                                                  const float* __restrict__ a,
                                                  const float* __restrict__ c,
                                                  unsigned short* __restrict__ Wout,
                                                  float* __restrict__ bout,
                                                  int Kdim, int nvalid) {
    int f = blockIdx.x, t = threadIdx.x;
    unsigned short* wo = Wout + (size_t)f * Kdim;
    if (f >= nvalid) {
        for (int col = t; col < Kdim; col += 256) wo[col] = 0;
        if (t == 0) bout[f] = 0.f;
        return;
    }
    const float* wr = W + (size_t)f * Kdim;
    float partial = 0.f;
    for (int col = t; col < Kdim; col += 256) {
        int j = col;
        if (PERM) {
            int x = col >> 7, jj = col & 127, pp = jj >> 4, d = jj & 15;
            j = (pp << 7) + (x << 4) + d;
        }
        float wv = wr[j];
        wo[col] = f2bf(wv * a[col]);
        partial = fmaf(wv, c[col], partial);
    }
    partial = waveSum(partial);
    __shared__ float sred[4];
    if ((t & 63) == 0) sred[t >> 6] = partial;
    __syncthreads();
    if (t == 0) bout[f] = bin[f] + sred[0] + sred[1] + sred[2] + sred[3];
}

// ---------- MFMA GEMM: C = A @ B^T, 128x128 tile, BK=64, 4 waves ----------
// Grid: x = flattened (ntm*ntn) with XCD swizzle, y = z (batched slabs).
// EPI 0 (A_F32): bf16 store, * rowinv computed inline from A's fp32 rows (cp)
// EPI 1: bf16 elu(x+bias); STATS -> col sum/sumsq partials ps/pq[mt][col]  (h)
// EPI 2: fp32 x+bias, col<nvalid     (out)
// EPI 3: fp32 x, col<nvalid, row<16  (logits, batched over z=p)
template <int EPI, bool A_F32, bool STATS>
__global__ __launch_bounds__(256) void gemm_mfma(const void* __restrict__ Av,
                                                 const unsigned short* __restrict__ Bv,
                                                 void* __restrict__ Cv, int K,
                                                 int ntn, int ldc, int nvalid,
                                                 const float* __restrict__ bias,
                                                 float* __restrict__ ps,
                                                 float* __restrict__ pq,
                                                 int aZ, int bZ, int cZ) {
    __shared__ unsigned short Asl[128 * 64];
    __shared__ unsigned short Bsl[128 * 64];
    __shared__ float extraA[128];
    __shared__ float extraB[128];
    const int tid = threadIdx.x;
    const int lane = tid & 63, wid = tid >> 6;
    const int wr = wid >> 1, wc = wid & 1;
    const int wg = xcd_swz(blockIdx.x, gridDim.x);
    const int m0 = (wg / ntn) * 128, n0 = (wg % ntn) * 128;
    const int z = blockIdx.y;

    const float* Af = (const float*)Av;
    const unsigned short* Ab = (const unsigned short*)Av + (size_t)z * aZ;
    const unsigned short* B = Bv + (size_t)z * bZ;

    f32x4 acc[4][4];
#pragma unroll
    for (int i = 0; i < 4; ++i)
#pragma unroll
        for (int j = 0; j < 4; ++j) acc[i][j] = {0.f, 0.f, 0.f, 0.f};

    const int swz = ((lane & 7) ^ (lane >> 3)) * 8;
    const int lrow = lane & 15, lkh = lane >> 4;
    float ssq[4] = {0.f, 0.f, 0.f, 0.f};

    for (int k0 = 0; k0 < K; k0 += 64) {
        if (A_F32) {
#pragma unroll
            for (int r = 0; r < 4; ++r) {
                int row = r * 32 + (tid >> 3);
                int kk = (tid & 7) * 8;
                const float* src = Af + (size_t)(m0 + row) * K + k0 + kk;
                float4 p0 = *(const float4*)src;
                float4 p1 = *(const float4*)(src + 4);
                ssq[r] += p0.x*p0.x + p0.y*p0.y + p0.z*p0.z + p0.w*p0.w
                        + p1.x*p1.x + p1.y*p1.y + p1.z*p1.z + p1.w*p1.w;
                bf16x8 v;
                v[0] = (short)f2bf(p0.x); v[1] = (short)f2bf(p0.y);
                v[2] = (short)f2bf(p0.z); v[3] = (short)f2bf(p0.w);
                v[4] = (short)f2bf(p1.x); v[5] = (short)f2bf(p1.y);
                v[6] = (short)f2bf(p1.z); v[7] = (short)f2bf(p1.w);
                *(bf16x8*)&Asl[row * 64 + (kk ^ ((row & 7) << 3))] = v;
            }
        } else {
#pragma unroll
            for (int r = 0; r < 4; ++r) {
                int row = r * 32 + wid * 8 + (lane >> 3);
                gload16(Ab + (size_t)(m0 + row) * K + k0 + swz,
                        Asl + r * 2048 + wid * 512);
            }
        }
#pragma unroll
        for (int r = 0; r < 4; ++r) {
            int row = r * 32 + wid * 8 + (lane >> 3);
            gload16(B + (size_t)(n0 + row) * K + k0 + swz,
                    Bsl + r * 2048 + wid * 512);
        }
        __syncthreads();
#pragma unroll
        for (int kk = 0; kk < 2; ++kk) {
            bf16x8 af[4], bfr[4];
#pragma unroll
            for (int m = 0; m < 4; ++m) {
                int row = wr * 64 + m * 16 + lrow;
                af[m] = *(const bf16x8*)&Asl[row * 64 + ((kk * 32 + lkh * 8) ^ ((row & 7) << 3))];
            }
#pragma unroll
            for (int n = 0; n < 4; ++n) {
                int row = wc * 64 + n * 16 + lrow;
                bfr[n] = *(const bf16x8*)&Bsl[row * 64 + ((kk * 32 + lkh * 8) ^ ((row & 7) << 3))];
            }
#pragma unroll
            for (int m = 0; m < 4; ++m)
#pragma unroll
                for (int n = 0; n < 4; ++n)
                    acc[m][n] = __builtin_amdgcn_mfma_f32_16x16x32_bf16(af[m], bfr[n], acc[m][n], 0, 0, 0);
        }
        __syncthreads();
    }

    if (A_F32) {
        // finish row sum-of-squares: 8 lanes per row share (tid&7)
#pragma unroll
        for (int r = 0; r < 4; ++r) {
            float s = ssq[r];
            s += __shfl_xor(s, 1); s += __shfl_xor(s, 2); s += __shfl_xor(s, 4);
            if ((tid & 7) == 0) extraA[r * 32 + (tid >> 3)] = 64.f / (sqrtf(s) + 1e-6f);
        }
        __syncthreads();
    }

    // epilogue — C/D layout: col = lane&15, row = (lane>>4)*4 + reg  [m89]
    const int colbase = n0 + wc * 64 + lrow;
    float bv[4];
    if (EPI == 1 || EPI == 2) {
#pragma unroll
        for (int n = 0; n < 4; ++n) bv[n] = bias[colbase + n * 16];
    }
    if (EPI == 0) {
        unsigned short* C = (unsigned short*)Cv;
#pragma unroll
        for (int m = 0; m < 4; ++m) {
            int rloc = wr * 64 + m * 16 + lkh * 4;
#pragma unroll
            for (int r = 0; r < 4; ++r) {
                float riv = extraA[rloc + r];
#pragma unroll
                for (int n = 0; n < 4; ++n)
                    C[(size_t)(m0 + rloc + r) * ldc + colbase + n * 16] = f2bf(acc[m][n][r] * riv);
            }
        }
    } else if (EPI == 1) {
        unsigned short* C = (unsigned short*)Cv;
        float sN[4] = {0.f, 0.f, 0.f, 0.f}, qN[4] = {0.f, 0.f, 0.f, 0.f};
#pragma unroll
        for (int m = 0; m < 4; ++m) {
            int row = m0 + wr * 64 + m * 16 + lkh * 4;
#pragma unroll
            for (int r = 0; r < 4; ++r)
#pragma unroll
                for (int n = 0; n < 4; ++n) {
                    float v = acc[m][n][r] + bv[n];
                    v = v > 0.f ? v : expm1f(v);
                    sN[n] += v;
                    qN[n] = fmaf(v, v, qN[n]);
                    C[(size_t)(row + r) * ldc + colbase + n * 16] = f2bf(v);
                }
        }
        if (STATS) {
            // reduce over lkh groups (lanes 16 apart hold different rows, same col)
#pragma unroll
            for (int n = 0; n < 4; ++n) {
                sN[n] += __shfl_xor(sN[n], 16); sN[n] += __shfl_xor(sN[n], 32);
                qN[n] += __shfl_xor(qN[n], 16); qN[n] += __shfl_xor(qN[n], 32);
            }
            __syncthreads();
            if (wr == 0 && lane < 16) {
#pragma unroll
                for (int n = 0; n < 4; ++n) {
                    extraA[wc * 64 + n * 16 + lrow] = sN[n];
                    extraB[wc * 64 + n * 16 + lrow] = qN[n];
                }
            }
            __syncthreads();
            if (wr == 1 && lane < 16) {
#pragma unroll
                for (int n = 0; n < 4; ++n) {
                    extraA[wc * 64 + n * 16 + lrow] += sN[n];
                    extraB[wc * 64 + n * 16 + lrow] += qN[n];
                }
            }
            __syncthreads();
            if (tid < 128) {
                int mt = wg / ntn;
                ps[(size_t)mt * ldc + n0 + tid] = extraA[tid];
                pq[(size_t)mt * ldc + n0 + tid] = extraB[tid];
            }
        }
    } else {
        float* C = (float*)Cv + (size_t)z * cZ;
#pragma unroll
        for (int m = 0; m < 4; ++m) {
            int row = m0 + wr * 64 + m * 16 + lkh * 4;
#pragma unroll
            for (int r = 0; r < 4; ++r) {
                if (EPI == 3 && (row + r) >= 16) continue;
#pragma unroll
                for (int n = 0; n < 4; ++n) {
                    int col = colbase + n * 16;
                    if (col < nvalid) {
                        float v = acc[m][n][r];
                        if (EPI == 2) v += bv[n];
                        C[(size_t)(row + r) * ldc + col] = v;
                    }
                }
            }
        }
    }
}

// ---------------- launch ----------------
extern "C" void kernel_launch(void* const* d_in, const int* in_sizes, int n_in,
                              void* d_out, int out_size, void* d_ws, size_t ws_size,
                              hipStream_t stream) {
    const float* img_f    = (const float*)d_in[0];   // (8192,8,512)
    const float* tex_f    = (const float*)d_in[1];   // (8,1000,512)
    const float* fake_cls = (const float*)d_in[2];   // (8,16,512)
    const float* fc_w     = (const float*)d_in[3];   // (512,512)
    const float* bn1_g    = (const float*)d_in[5];   // (1024)
    const float* bn1_b    = (const float*)d_in[6];
    const float* w1       = (const float*)d_in[7];   // (2048,1024)
    const float* b1       = (const float*)d_in[8];
    const float* bn2_g    = (const float*)d_in[9];   // (2048)
    const float* bn2_b    = (const float*)d_in[10];
    const float* w2       = (const float*)d_in[11];  // (1000,2048)
    const float* b2       = (const float*)d_in[12];
    float* out = (float*)d_out;

    char* w = (char*)d_ws;   // byte offsets; total ~69 MB
    unsigned short* texn = (unsigned short*)(w);             // 8,388,608 (8000 rows + pad)
    unsigned short* g_bf = (unsigned short*)(w + 8388608);   //   262,144 (128 rows + pad)
    float*          logit= (float*)(w + 8650752);            //   524,288 (128x1000)
    float*          part = (float*)(w + 9175040);            // 4,194,304 (16x8x16x512)
    unsigned short* texa = (unsigned short*)(w + 13369344);  //   131,072
    unsigned short* cp   = (unsigned short*)(w + 13500416);  // 16,777,216
    unsigned short* w1a  = (unsigned short*)(w + 30277632);  //  4,194,304
    float*          b1p  = (float*)(w + 34471936);           //      8,192
    float*          a1   = (float*)(w + 34480128);
    float*          c1   = (float*)(w + 34484224);
    float*          ps   = (float*)(w + 34488320);           //    524,288
    float*          pq   = (float*)(w + 35012608);           //    524,288
    unsigned short* h    = (unsigned short*)(w + 35536896);  // 33,554,432
    unsigned short* w2a  = (unsigned short*)(w + 69091328);  //  4,194,304
    float*          b2p  = (float*)(w + 73285632);
    float*          a2   = (float*)(w + 73289728);
    float*          c2   = (float*)(w + 73297920);

    // ---- attention path ----
    k_prep<<<8128, 256, 0, stream>>>(tex_f, texn, fake_cls, fc_w, g_bf);
    gemm_mfma<3, false, false><<<dim3(8, 8), 256, 0, stream>>>(
        g_bf, texn, logit, 512, 8, 1000, 1000, nullptr, nullptr, nullptr,
        16 * 512, 1000 * 512, 16 * 1000);
    k_wsum_sm<<<dim3(16, 8), 256, 0, stream>>>(logit, texn, part);
    k_texa_red<<<128, 256, 0, stream>>>(part, texa);

    // ---- cp' = (img @ texa^T)*inv -> bf16, permuted cols (65536 x 128) ----
    gemm_mfma<0, true, false><<<dim3(512, 1), 256, 0, stream>>>(
        img_f, texa, cp, 512, 1, 128, 128, nullptr, nullptr, nullptr, 0, 0, 0);

    // ---- BN1 -> fold into w1 (column permutation) ----
    k_colstat_bf<<<dim3(4, 64), 256, 0, stream>>>(cp, ps, pq, 1024);
    k_bnfin<true><<<4, 256, 0, stream>>>(ps, pq, bn1_g, bn1_b, a1, c1, 1024);
    k_foldw_bf<true><<<2048, 256, 0, stream>>>(w1, b1, a1, c1, w1a, b1p, 1024, 2048);

    // ---- h = elu(cp' @ w1a^T + b1p) -> bf16, col-stats fused ----
    gemm_mfma<1, false, true><<<dim3(1024, 1), 256, 0, stream>>>(
        cp, w1a, h, 1024, 16, 2048, 2048, b1p, ps, pq, 0, 0, 0);

    // ---- BN2 -> fold into w2 (pad rows to 1024) ----
    k_bnfin<false><<<8, 256, 0, stream>>>(ps, pq, bn2_g, bn2_b, a2, c2, 2048);
    k_foldw_bf<false><<<1024, 256, 0, stream>>>(w2, b2, a2, c2, w2a, b2p, 2048, 1000);

    // ---- out = h @ w2a^T + b2p -> fp32 ----
    gemm_mfma<2, false, false><<<dim3(512, 1), 256, 0, stream>>>(
        h, w2a, out, 2048, 8, 1000, 1000, b2p, nullptr, nullptr, 0, 0, 0);
}

// Round 5
// 240.848 us; speedup vs baseline: 5.9412x; 1.0367x over previous
//
#include <hip/hip_runtime.h>
#include <math.h>

// B=8192, X=8, C=512, P=8, Y=1000, FAKE=16, F=2048, CLS=1000, IN_DIM=1024, SF=64
//
// Pipeline (12 launches):
//  k_prep:   texn = rownorm(tex_f)->bf16  |  g_bf = fake_cls @ fc_w ->bf16
//  logits[p] = g_bf[p] @ texn[p]^T            [MFMA128 EPI3, z=p]
//  k_wsum_sm: softmax(logits) fused, partial texa sums
//  k_texa_red: reduce -> texa bf16
//  cp' = (img @ texa^T) * inv_row             [MFMA128 EPI0, A fp32 reg-staged,
//                                              row-norm inline, out bf16, permuted cols]
//  colstat(cp) -> bnfin1 -> foldw1 (perm)     [bf16 weights]
//  h = elu(cp' @ w1a^T + b1p)                 [gemm256 FM=8 NH=2, counted-vmcnt pipeline,
//                                              col-stats fused -> ps/pq (64 rows)]
//  bnfin2 -> foldw2 (pad 1024)                [bf16 weights]
//  out = h @ w2a^T + b2p                      [gemm256 FM=4 NH=2, fp32]

typedef __attribute__((ext_vector_type(8))) short bf16x8;
typedef __attribute__((ext_vector_type(4))) float f32x4;

__device__ __forceinline__ float waveSum(float v) {
#pragma unroll
    for (int o = 32; o > 0; o >>= 1) v += __shfl_xor(v, o);
    return v;
}
__device__ __forceinline__ float waveMax(float v) {
#pragma unroll
    for (int o = 32; o > 0; o >>= 1) v = fmaxf(v, __shfl_xor(v, o));
    return v;
}
__device__ __forceinline__ unsigned short f2bf(float x) {
    union { float f; unsigned u; } v; v.f = x;
    unsigned r = v.u + 0x7FFFu + ((v.u >> 16) & 1u);
    return (unsigned short)(r >> 16);
}
__device__ __forceinline__ float bf2f(unsigned short h) {
    union { unsigned u; float f; } v; v.u = ((unsigned)h) << 16; return v.f;
}
__device__ __forceinline__ void gload16(const void* g, const void* l) {
    __builtin_amdgcn_global_load_lds((const __attribute__((address_space(1))) void*)g,
                                     (__attribute__((address_space(3))) void*)l, 16, 0, 0);
}
__device__ __forceinline__ int xcd_swz(int d, int n) {
    int q = n >> 3;                     // all gemm grids are %8==0
    return (d & 7) * q + (d >> 3);
}
#define SBAR __builtin_amdgcn_sched_barrier(0)

// ---------- fused: rownorm(tex_f)->texn bf16 (blocks 0..7999), g_bf (8000..8127) ----------
__global__ __launch_bounds__(256) void k_prep(const float* __restrict__ tex_f,
                                              unsigned short* __restrict__ texn,
                                              const float* __restrict__ fake_cls,
                                              const float* __restrict__ fc_w,
                                              unsigned short* __restrict__ g_bf) {
    __shared__ float sred[4];
    __shared__ float fcls[512];
    int bid = blockIdx.x, t = threadIdx.x;
    if (bid < 8000) {
        const float* r = tex_f + (size_t)bid * 512;
        float2 v = *(const float2*)(r + t * 2);
        float ss = v.x * v.x + v.y * v.y;
        ss = waveSum(ss);
        if ((t & 63) == 0) sred[t >> 6] = ss;
        __syncthreads();
        float tot = sred[0] + sred[1] + sred[2] + sred[3];
        float sc = 64.f / (sqrtf(tot) + 1e-6f);
        unsigned u = (unsigned)f2bf(v.x * sc) | ((unsigned)f2bf(v.y * sc) << 16);
        *(unsigned*)(texn + (size_t)bid * 512 + t * 2) = u;
    } else {
        int row = bid - 8000;
        fcls[t]       = fake_cls[row * 512 + t];
        fcls[t + 256] = fake_cls[row * 512 + t + 256];
        __syncthreads();
        float a0 = 0.f, a1 = 0.f;
        for (int d = 0; d < 512; ++d) {
            float fv = fcls[d];
            a0 = fmaf(fv, fc_w[d * 512 + t], a0);
            a1 = fmaf(fv, fc_w[d * 512 + t + 256], a1);
        }
        g_bf[row * 512 + t]       = f2bf(a0);
        g_bf[row * 512 + t + 256] = f2bf(a1);
    }
}

// ---------- wsum with fused softmax: block (yt 0..15, p 0..7) ----------
__global__ __launch_bounds__(256) void k_wsum_sm(const float* __restrict__ logit,
                                                 const unsigned short* __restrict__ texn,
                                                 float* __restrict__ part) {
    int yt = blockIdx.x, p = blockIdx.y, t = threadIdx.x;
    int lane = t & 63, w = t >> 6;
    __shared__ float wl[16][63];
    __shared__ float ms[16], iss[16];
    const int y0 = yt * 63;
    const int ylen = min(63, 1000 - y0);
#pragma unroll
    for (int rr = 0; rr < 4; ++rr) {
        int x = w * 4 + rr;
        const float* lr = logit + ((size_t)p * 16 + x) * 1000;
        float m = -3.0e38f;
        for (int y = lane; y < 1000; y += 64) m = fmaxf(m, lr[y]);
        m = waveMax(m);
        float s = 0.f;
        for (int y = lane; y < 1000; y += 64) s += expf(lr[y] - m);
        s = waveSum(s);
        if (lane == 0) { ms[x] = m; iss[x] = 1.f / s; }
    }
    __syncthreads();
    for (int idx = t; idx < 16 * ylen; idx += 256) {
        int x = idx / ylen, y = idx % ylen;
        wl[x][y] = expf(logit[((size_t)p * 16 + x) * 1000 + y0 + y] - ms[x]) * iss[x];
    }
    __syncthreads();
    int c0 = t * 2;
    const unsigned short* tp = texn + ((size_t)p * 1000 + y0) * 512 + c0;
    float a0[16], a1[16];
#pragma unroll
    for (int x = 0; x < 16; ++x) { a0[x] = 0.f; a1[x] = 0.f; }
    for (int y = 0; y < ylen; ++y) {
        unsigned u = *(const unsigned*)(tp + (size_t)y * 512);
        float lo = bf2f((unsigned short)(u & 0xffff));
        float hi = bf2f((unsigned short)(u >> 16));
#pragma unroll
        for (int x = 0; x < 16; ++x) {
            float ww = wl[x][y];
            a0[x] = fmaf(ww, lo, a0[x]);
            a1[x] = fmaf(ww, hi, a1[x]);
        }
    }
#pragma unroll
    for (int x = 0; x < 16; ++x) {
        float* dst = part + ((size_t)((yt * 8 + p) * 16 + x)) * 512 + c0;
        dst[0] = a0[x];
        dst[1] = a1[x];
    }
}

// ---------- reduce 16 y-partials -> texa bf16 ----------
__global__ __launch_bounds__(256) void k_texa_red(const float* __restrict__ part,
                                                  unsigned short* __restrict__ texa) {
    int row = blockIdx.x, t = threadIdx.x;      // row = p*16 + x
    int p = row >> 4, x = row & 15;
    int c = t * 2;
    float s0 = 0.f, s1 = 0.f;
#pragma unroll
    for (int yt = 0; yt < 16; ++yt) {
        const float* src = part + ((size_t)((yt * 8 + p) * 16 + x)) * 512 + c;
        s0 += src[0];
        s1 += src[1];
    }
    unsigned u = (unsigned)f2bf(s0) | ((unsigned)f2bf(s1) << 16);
    *(unsigned*)(texa + (size_t)row * 512 + c) = u;
}

// ---------- column stats over bf16 matrix (cp): 128 rows per y-block ----------
__global__ __launch_bounds__(256) void k_colstat_bf(const unsigned short* __restrict__ src,
                                                    float* __restrict__ ps,
                                                    float* __restrict__ pq, int ncols) {
    int col = blockIdx.x * 256 + threadIdx.x;
    int r0 = blockIdx.y * 128;
    const unsigned short* p = src + (size_t)r0 * ncols + col;
    float s = 0.f, q = 0.f;
    for (int r = 0; r < 128; ++r) {
        float v = bf2f(p[(size_t)r * ncols]);
        s += v;
        q = fmaf(v, v, q);
    }
    ps[(size_t)blockIdx.y * ncols + col] = s;
    pq[(size_t)blockIdx.y * ncols + col] = q;
}

// ---------- finalize BN scale/shift; PERM maps permuted col' -> true j ----------
template <bool PERM>
__global__ __launch_bounds__(256) void k_bnfin(const float* __restrict__ ps,
                                               const float* __restrict__ pq,
                                               const float* __restrict__ gam,
                                               const float* __restrict__ bet,
                                               float* __restrict__ a, float* __restrict__ c,
                                               int ncols) {
    int col = blockIdx.x * 256 + threadIdx.x;
    float S = 0.f, Q = 0.f;
    for (int i = 0; i < 64; ++i) {
        S += ps[(size_t)i * ncols + col];
        Q += pq[(size_t)i * ncols + col];
    }
    float mean = S * (1.f / 8192.f);
    float var = Q * (1.f / 8192.f) - mean * mean;
    int j = col;
    if (PERM) {
        int x = col >> 7, jj = col & 127, pp = jj >> 4, d = jj & 15;
        j = (pp << 7) + (x << 4) + d;
    }
    float av = gam[j] * rsqrtf(var + 1e-5f);
    a[col] = av;
    c[col] = bet[j] - mean * av;
}

// ---------- fold BN into weights -> bf16 ----------
template <bool PERM>
__global__ __launch_bounds__(256) void k_foldw_bf(const float* __restrict__ W,
                                                  const float* __restrict__ bin,
                                                  const float* __restrict__ a,
                                                  const float* __restrict__ c,
                                                  unsigned short* __restrict__ Wout,
                                                  float* __restrict__ bout,
                                                  int Kdim, int nvalid) {
    int f = blockIdx.x, t = threadIdx.x;
    unsigned short* wo = Wout + (size_t)f * Kdim;
    if (f >= nvalid) {
        for (int col = t; col < Kdim; col += 256) wo[col] = 0;
        if (t == 0) bout[f] = 0.f;
        return;
    }
    const float* wr = W + (size_t)f * Kdim;
    float partial = 0.f;
    for (int col = t; col < Kdim; col += 256) {
        int j = col;
        if (PERM) {
            int x = col >> 7, jj = col & 127, pp = jj >> 4, d = jj & 15;
            j = (pp << 7) + (x << 4) + d;
        }
        float wv = wr[j];
        wo[col] = f2bf(wv * a[col]);
        partial = fmaf(wv, c[col], partial);
    }
    partial = waveSum(partial);
    __shared__ float sred[4];
    if ((t & 63) == 0) sred[t >> 6] = partial;
    __syncthreads();
    if (t == 0) bout[f] = bin[f] + sred[0] + sred[1] + sred[2] + sred[3];
}

// ---------- small MFMA GEMM (128x128 tile, 4 waves) for cp & logits ----------
// EPI 0 (A_F32): bf16 store * rowinv computed inline from A's fp32 rows (cp)
// EPI 3: fp32 store, col<nvalid, row<16 (logits, batched over z=p)
template <int EPI, bool A_F32>
__global__ __launch_bounds__(256) void gemm_mfma(const void* __restrict__ Av,
                                                 const unsigned short* __restrict__ Bv,
                                                 void* __restrict__ Cv, int K,
                                                 int ntn, int ldc, int nvalid,
                                                 int aZ, int bZ, int cZ) {
    __shared__ unsigned short Asl[128 * 64];
    __shared__ unsigned short Bsl[128 * 64];
    __shared__ float rowinv[128];
    const int tid = threadIdx.x;
    const int lane = tid & 63, wid = tid >> 6;
    const int wr = wid >> 1, wc = wid & 1;
    const int wg = xcd_swz(blockIdx.x, gridDim.x);
    const int m0 = (wg / ntn) * 128, n0 = (wg % ntn) * 128;
    const int z = blockIdx.y;

    const float* Af = (const float*)Av;
    const unsigned short* Ab = (const unsigned short*)Av + (size_t)z * aZ;
    const unsigned short* B = Bv + (size_t)z * bZ;

    f32x4 acc[4][4];
#pragma unroll
    for (int i = 0; i < 4; ++i)
#pragma unroll
        for (int j = 0; j < 4; ++j) acc[i][j] = {0.f, 0.f, 0.f, 0.f};

    const int swz = ((lane & 7) ^ (lane >> 3)) * 8;
    const int lrow = lane & 15, lkh = lane >> 4;
    float ssq[4] = {0.f, 0.f, 0.f, 0.f};

    for (int k0 = 0; k0 < K; k0 += 64) {
        if (A_F32) {
#pragma unroll
            for (int r = 0; r < 4; ++r) {
                int row = r * 32 + (tid >> 3);
                int kk = (tid & 7) * 8;
                const float* src = Af + (size_t)(m0 + row) * K + k0 + kk;
                float4 p0 = *(const float4*)src;
                float4 p1 = *(const float4*)(src + 4);
                ssq[r] += p0.x*p0.x + p0.y*p0.y + p0.z*p0.z + p0.w*p0.w
                        + p1.x*p1.x + p1.y*p1.y + p1.z*p1.z + p1.w*p1.w;
                bf16x8 v;
                v[0] = (short)f2bf(p0.x); v[1] = (short)f2bf(p0.y);
                v[2] = (short)f2bf(p0.z); v[3] = (short)f2bf(p0.w);
                v[4] = (short)f2bf(p1.x); v[5] = (short)f2bf(p1.y);
                v[6] = (short)f2bf(p1.z); v[7] = (short)f2bf(p1.w);
                *(bf16x8*)&Asl[row * 64 + (kk ^ ((row & 7) << 3))] = v;
            }
        } else {
#pragma unroll
            for (int r = 0; r < 4; ++r) {
                int row = r * 32 + wid * 8 + (lane >> 3);
                gload16(Ab + (size_t)(m0 + row) * K + k0 + swz,
                        Asl + r * 2048 + wid * 512);
            }
        }
#pragma unroll
        for (int r = 0; r < 4; ++r) {
            int row = r * 32 + wid * 8 + (lane >> 3);
            gload16(B + (size_t)(n0 + row) * K + k0 + swz,
                    Bsl + r * 2048 + wid * 512);
        }
        __syncthreads();
#pragma unroll
        for (int kk = 0; kk < 2; ++kk) {
            bf16x8 af[4], bfr[4];
#pragma unroll
            for (int m = 0; m < 4; ++m) {
                int row = wr * 64 + m * 16 + lrow;
                af[m] = *(const bf16x8*)&Asl[row * 64 + ((kk * 32 + lkh * 8) ^ ((row & 7) << 3))];
            }
#pragma unroll
            for (int n = 0; n < 4; ++n) {
                int row = wc * 64 + n * 16 + lrow;
                bfr[n] = *(const bf16x8*)&Bsl[row * 64 + ((kk * 32 + lkh * 8) ^ ((row & 7) << 3))];
            }
#pragma unroll
            for (int m = 0; m < 4; ++m)
#pragma unroll
                for (int n = 0; n < 4; ++n)
                    acc[m][n] = __builtin_amdgcn_mfma_f32_16x16x32_bf16(af[m], bfr[n], acc[m][n], 0, 0, 0);
        }
        __syncthreads();
    }

    if (A_F32) {
#pragma unroll
        for (int r = 0; r < 4; ++r) {
            float s = ssq[r];
            s += __shfl_xor(s, 1); s += __shfl_xor(s, 2); s += __shfl_xor(s, 4);
            if ((tid & 7) == 0) rowinv[r * 32 + (tid >> 3)] = 64.f / (sqrtf(s) + 1e-6f);
        }
        __syncthreads();
    }

    const int colbase = n0 + wc * 64 + lrow;
    if (EPI == 0) {
        unsigned short* C = (unsigned short*)Cv;
#pragma unroll
        for (int m = 0; m < 4; ++m) {
            int rloc = wr * 64 + m * 16 + lkh * 4;
#pragma unroll
            for (int r = 0; r < 4; ++r) {
                float riv = rowinv[rloc + r];
#pragma unroll
                for (int n = 0; n < 4; ++n)
                    C[(size_t)(m0 + rloc + r) * ldc + colbase + n * 16] = f2bf(acc[m][n][r] * riv);
            }
        }
    } else {
        float* C = (float*)Cv + (size_t)z * cZ;
#pragma unroll
        for (int m = 0; m < 4; ++m) {
            int row = m0 + wr * 64 + m * 16 + lkh * 4;
#pragma unroll
            for (int r = 0; r < 4; ++r) {
                if ((row + r) >= 16) continue;
#pragma unroll
                for (int n = 0; n < 4; ++n) {
                    int col = colbase + n * 16;
                    if (col < nvalid) C[(size_t)(row + r) * ldc + col] = acc[m][n][r];
                }
            }
        }
    }
}

// ---------- big MFMA GEMM: counted-vmcnt pipelined, 8 waves, 512 threads ----------
// BM = FM*32 (FM=8 -> 256, FM=4 -> 128), BN = NH*128 (=256).
// Waves: 2 (M) x 4 (N); per-wave output = (BM/2) x 64 = FM x 4 frags of 16x16.
// LDS: double-buffered K-tiles (BK=64), A MH halves + B NH halves of [128][64] bf16,
// XOR-swizzled (same granule scheme as the 128 kernel, both sides verified).
// Schedule per K-tile kt (buffers buf[kt&1], 2-deep prefetch):
//   ds_read kk0 frags -> MFMA kk0 -> ds_read kk1 frags
//   lgkmcnt(0); s_barrier            // all waves' reads of buf[cur] retired
//   stage(kt+2 -> buf[cur]); s_waitcnt vmcnt(LA)   // kt+1's loads landed; kt+2 in flight
//   s_barrier                         // buf[cur^1] globally ready
//   MFMA kk1 (overlaps kt+2's flight + next iter's reads)
// EPI 1: bf16 elu(x+bias), fused col stats -> ps/pq[(mt*2+wm)][col] (64 rows total)
// EPI 2: fp32 x+bias, col<nvalid
template <int FM, int NH, int EPI>
__global__ __launch_bounds__(512, 2) void gemm256(const unsigned short* __restrict__ A,
                                                  const unsigned short* __restrict__ B,
                                                  void* __restrict__ Cv, int K,
                                                  int ntn, int ldc, int nvalid,
                                                  const float* __restrict__ bias,
                                                  float* __restrict__ ps,
                                                  float* __restrict__ pq) {
    constexpr int BM = FM * 32;
    constexpr int MH = BM / 128;
    constexpr int BN = NH * 128;
    constexpr int LA = 2 * (MH + NH);   // gloads per thread per K-tile
    __shared__ unsigned short Asl[2][MH][128 * 64];
    __shared__ unsigned short Bsl[2][NH][128 * 64];
    const int tid = threadIdx.x;
    const int lane = tid & 63, wid = tid >> 6;
    const int wm = wid >> 2, wn = wid & 3;
    const int wg = xcd_swz(blockIdx.x, gridDim.x);
    const int m0 = (wg / ntn) * BM, n0 = (wg % ntn) * BN;
    const int lrow = lane & 15, lkh = lane >> 4;
    const int l7 = lane & 7;
    const int ksrc = ((lane & 7) ^ (lane >> 3)) * 8;
    const int mbase = wm * (BM / 2);
    const int mhalf = mbase >> 7;
    const int mloc0 = mbase & 127;
    const int nbase = wn * 64;
    const int nhalf = nbase >> 7;
    const int nloc0 = nbase & 127;

    f32x4 acc[FM][4];
#pragma unroll
    for (int m = 0; m < FM; ++m)
#pragma unroll
        for (int n = 0; n < 4; ++n) acc[m][n] = {0.f, 0.f, 0.f, 0.f};

    const int nkt = K >> 6;

    auto stage = [&](int kt, int buf) {
#pragma unroll
        for (int hf = 0; hf < MH; ++hf)
#pragma unroll
            for (int j = 0; j < 2; ++j) {
                int rl = wid * 16 + j * 8 + (lane >> 3);
                gload16(A + (size_t)(m0 + hf * 128 + rl) * K + kt * 64 + ksrc,
                        &Asl[buf][hf][(wid * 16 + j * 8) * 64]);
            }
#pragma unroll
        for (int hf = 0; hf < NH; ++hf)
#pragma unroll
            for (int j = 0; j < 2; ++j) {
                int rl = wid * 16 + j * 8 + (lane >> 3);
                gload16(B + (size_t)(n0 + hf * 128 + rl) * K + kt * 64 + ksrc,
                        &Bsl[buf][hf][(wid * 16 + j * 8) * 64]);
            }
    };

    // prologue: fill both buffers; wait for buf0 only (buf1 stays in flight)
    stage(0, 0);
    stage(1, 1);
    if constexpr (LA == 8) asm volatile("s_waitcnt vmcnt(8)" ::: "memory");
    else asm volatile("s_waitcnt vmcnt(6)" ::: "memory");
    SBAR; __builtin_amdgcn_s_barrier(); SBAR;

    for (int kt = 0; kt < nkt; ++kt) {
        const int cur = kt & 1;
        // ---- kk0 fragment reads ----
        bf16x8 af0[FM], bf0[4];
#pragma unroll
        for (int m = 0; m < FM; ++m) {
            int row = mloc0 + m * 16 + lrow;
            af0[m] = *(const bf16x8*)&Asl[cur][mhalf][row * 64 + ((lkh ^ l7) << 3)];
        }
#pragma unroll
        for (int n = 0; n < 4; ++n) {
            int row = nloc0 + n * 16 + lrow;
            bf0[n] = *(const bf16x8*)&Bsl[cur][nhalf][row * 64 + ((lkh ^ l7) << 3)];
        }
        // ---- kk0 MFMA ----
        __builtin_amdgcn_s_setprio(1);
#pragma unroll
        for (int m = 0; m < FM; ++m)
#pragma unroll
            for (int n = 0; n < 4; ++n)
                acc[m][n] = __builtin_amdgcn_mfma_f32_16x16x32_bf16(af0[m], bf0[n], acc[m][n], 0, 0, 0);
        __builtin_amdgcn_s_setprio(0);
        // ---- kk1 fragment reads ----
        bf16x8 af1[FM], bf1[4];
#pragma unroll
        for (int m = 0; m < FM; ++m) {
            int row = mloc0 + m * 16 + lrow;
            af1[m] = *(const bf16x8*)&Asl[cur][mhalf][row * 64 + (((4 + lkh) ^ l7) << 3)];
        }
#pragma unroll
        for (int n = 0; n < 4; ++n) {
            int row = nloc0 + n * 16 + lrow;
            bf1[n] = *(const bf16x8*)&Bsl[cur][nhalf][row * 64 + (((4 + lkh) ^ l7) << 3)];
        }
        if (kt + 1 < nkt) {
            asm volatile("s_waitcnt lgkmcnt(0)" ::: "memory");
            SBAR; __builtin_amdgcn_s_barrier(); SBAR;
            if (kt + 2 < nkt) {
                stage(kt + 2, cur);
                if constexpr (LA == 8) asm volatile("s_waitcnt vmcnt(8)" ::: "memory");
                else asm volatile("s_waitcnt vmcnt(6)" ::: "memory");
            } else {
                asm volatile("s_waitcnt vmcnt(0)" ::: "memory");
            }
            SBAR; __builtin_amdgcn_s_barrier(); SBAR;
        }
        // ---- kk1 MFMA (register-only; overlaps kt+2 flight & next reads) ----
        __builtin_amdgcn_s_setprio(1);
#pragma unroll
        for (int m = 0; m < FM; ++m)
#pragma unroll
            for (int n = 0; n < 4; ++n)
                acc[m][n] = __builtin_amdgcn_mfma_f32_16x16x32_bf16(af1[m], bf1[n], acc[m][n], 0, 0, 0);
        __builtin_amdgcn_s_setprio(0);
    }

    // ---- epilogue ----
    const int colbase = n0 + nbase + lrow;
    if (EPI == 1) {
        unsigned short* C = (unsigned short*)Cv;
        float bv[4], sN[4] = {0.f, 0.f, 0.f, 0.f}, qN[4] = {0.f, 0.f, 0.f, 0.f};
#pragma unroll
        for (int n = 0; n < 4; ++n) bv[n] = bias[colbase + n * 16];
#pragma unroll
        for (int m = 0; m < FM; ++m) {
            int row = m0 + mbase + m * 16 + lkh * 4;
#pragma unroll
            for (int r = 0; r < 4; ++r)
#pragma unroll
                for (int n = 0; n < 4; ++n) {
                    float v = acc[m][n][r] + bv[n];
                    v = v > 0.f ? v : expm1f(v);
                    sN[n] += v;
                    qN[n] = fmaf(v, v, qN[n]);
                    C[(size_t)(row + r) * ldc + colbase + n * 16] = f2bf(v);
                }
        }
#pragma unroll
        for (int n = 0; n < 4; ++n) {
            sN[n] += __shfl_xor(sN[n], 16); sN[n] += __shfl_xor(sN[n], 32);
            qN[n] += __shfl_xor(qN[n], 16); qN[n] += __shfl_xor(qN[n], 32);
        }
        if (lane < 16) {
            int mt = wg / ntn;
#pragma unroll
            for (int n = 0; n < 4; ++n) {
                ps[(size_t)(mt * 2 + wm) * ldc + colbase + n * 16] = sN[n];
                pq[(size_t)(mt * 2 + wm) * ldc + colbase + n * 16] = qN[n];
            }
        }
    } else {
        float* C = (float*)Cv;
        float bv[4];
#pragma unroll
        for (int n = 0; n < 4; ++n) bv[n] = bias[colbase + n * 16];
#pragma unroll
        for (int m = 0; m < FM; ++m) {
            int row = m0 + mbase + m * 16 + lkh * 4;
#pragma unroll
            for (int r = 0; r < 4; ++r)
#pragma unroll
                for (int n = 0; n < 4; ++n) {
                    int col = colbase + n * 16;
                    if (col < nvalid) C[(size_t)(row + r) * ldc + col] = acc[m][n][r] + bv[n];
                }
        }
    }
}

// ---------------- launch ----------------
extern "C" void kernel_launch(void* const* d_in, const int* in_sizes, int n_in,
                              void* d_out, int out_size, void* d_ws, size_t ws_size,
                              hipStream_t stream) {
    const float* img_f    = (const float*)d_in[0];   // (8192,8,512)
    const float* tex_f    = (const float*)d_in[1];   // (8,1000,512)
    const float* fake_cls = (const float*)d_in[2];   // (8,16,512)
    const float* fc_w     = (const float*)d_in[3];   // (512,512)
    const float* bn1_g    = (const float*)d_in[5];   // (1024)
    const float* bn1_b    = (const float*)d_in[6];
    const float* w1       = (const float*)d_in[7];   // (2048,1024)
    const float* b1       = (const float*)d_in[8];
    const float* bn2_g    = (const float*)d_in[9];   // (2048)
    const float* bn2_b    = (const float*)d_in[10];
    const float* w2       = (const float*)d_in[11];  // (1000,2048)
    const float* b2       = (const float*)d_in[12];
    float* out = (float*)d_out;

    char* w = (char*)d_ws;   // byte offsets; total ~73.3 MB
    unsigned short* texn = (unsigned short*)(w);             // 8,388,608 (8000 rows + pad)
    unsigned short* g_bf = (unsigned short*)(w + 8388608);   //   262,144 (128 rows + pad)
    float*          logit= (float*)(w + 8650752);            //   524,288 (128x1000)
    float*          part = (float*)(w + 9175040);            // 4,194,304 (16x8x16x512)
    unsigned short* texa = (unsigned short*)(w + 13369344);  //   131,072
    unsigned short* cp   = (unsigned short*)(w + 13500416);  // 16,777,216
    unsigned short* w1a  = (unsigned short*)(w + 30277632);  //  4,194,304
    float*          b1p  = (float*)(w + 34471936);           //      8,192
    float*          a1   = (float*)(w + 34480128);
    float*          c1   = (float*)(w + 34484224);
    float*          ps   = (float*)(w + 34488320);           //    524,288
    float*          pq   = (float*)(w + 35012608);           //    524,288
    unsigned short* h    = (unsigned short*)(w + 35536896);  // 33,554,432
    unsigned short* w2a  = (unsigned short*)(w + 69091328);  //  4,194,304
    float*          b2p  = (float*)(w + 73285632);
    float*          a2   = (float*)(w + 73289728);
    float*          c2   = (float*)(w + 73297920);

    // ---- attention path ----
    k_prep<<<8128, 256, 0, stream>>>(tex_f, texn, fake_cls, fc_w, g_bf);
    gemm_mfma<3, false><<<dim3(8, 8), 256, 0, stream>>>(
        g_bf, texn, logit, 512, 8, 1000, 1000, 16 * 512, 1000 * 512, 16 * 1000);
    k_wsum_sm<<<dim3(16, 8), 256, 0, stream>>>(logit, texn, part);
    k_texa_red<<<128, 256, 0, stream>>>(part, texa);

    // ---- cp' = (img @ texa^T)*inv -> bf16, permuted cols (65536 x 128) ----
    gemm_mfma<0, true><<<dim3(512, 1), 256, 0, stream>>>(
        img_f, texa, cp, 512, 1, 128, 128, 0, 0, 0);

    // ---- BN1 -> fold into w1 (column permutation) ----
    k_colstat_bf<<<dim3(4, 64), 256, 0, stream>>>(cp, ps, pq, 1024);
    k_bnfin<true><<<4, 256, 0, stream>>>(ps, pq, bn1_g, bn1_b, a1, c1, 1024);
    k_foldw_bf<true><<<2048, 256, 0, stream>>>(w1, b1, a1, c1, w1a, b1p, 1024, 2048);

    // ---- h = elu(cp' @ w1a^T + b1p) -> bf16, col-stats fused (256x256 tiles) ----
    gemm256<8, 2, 1><<<dim3(256), 512, 0, stream>>>(
        cp, w1a, h, 1024, 8, 2048, 2048, b1p, ps, pq);

    // ---- BN2 -> fold into w2 (pad rows to 1024) ----
    k_bnfin<false><<<8, 256, 0, stream>>>(ps, pq, bn2_g, bn2_b, a2, c2, 2048);
    k_foldw_bf<false><<<1024, 256, 0, stream>>>(w2, b2, a2, c2, w2a, b2p, 2048, 1000);

    // ---- out = h @ w2a^T + b2p -> fp32 (128x256 tiles) ----
    gemm256<4, 2, 2><<<dim3(256), 512, 0, stream>>>(
        h, w2a, out, 2048, 4, 1000, 1000, b2p, nullptr, nullptr);
}